// Round 6
// baseline (404.188 us; speedup 1.0000x reference)
//
#include <hip/hip_runtime.h>

// ---------------------------------------------------------------------------
// MultiHeadedAttention fused pipeline for MI355X (gfx950), bf16 MFMA.
// B=1, S=4096, D=768, H=12, DH=64.
// Round 6: attack k_attn latency-boundness (was 359us, Occ 35%, Mfma 6%):
//   1. split-K x2 -> 1536 blocks (24 waves/CU) + combine kernel
//   2. lsum cross-lane reduce deferred to epilogue (-16 shfl/iter)
//   3. defer-max THR=8 (skip rescale most iters)
// Workspace layout (bytes):
//   xb   [4096][768] bf16          @ 0         (6291456)
//   wT   [3][12][64][768] bf16     @ 6291456   (3538944)
//   woT  [768][768] bf16           @ 9830400   (1179648)
//   q    [12][4096][64] bf16       @ 11010048  (6291456)  (pre-scaled 1/8)
//   k    [12][4096][64] bf16       @ 17301504  (6291456)
//   vT   [12][64][4096] bf16       @ 23592960  (6291456)
//   ctx  [4096][768] bf16          @ 29884416  (6291456)
//   oP   [2][12][4096][64] bf16    @ 36175872  (12582912)  (split-K partials)
//   mlP  [2][12][4096][2] f32      @ 48758784  (786432)
// total 49545216 <= 50331648 (ws >= 48MiB proven round 4).
// ---------------------------------------------------------------------------

using frag8 = __attribute__((ext_vector_type(8))) short;   // 8 x bf16 (4 VGPRs)
using facc4 = __attribute__((ext_vector_type(4))) float;   // MFMA accumulator

#define LOG2E 1.4426950408889634f
#define DEFER_THR 8.0f

#if defined(__has_builtin)
#  if __has_builtin(__builtin_amdgcn_exp2f)
#    define EXP2(x) __builtin_amdgcn_exp2f(x)
#  else
#    define EXP2(x) exp2f(x)
#  endif
#else
#  define EXP2(x) exp2f(x)
#endif

__device__ __forceinline__ unsigned short f2bf(float f) {
  unsigned int u = __builtin_bit_cast(unsigned int, f);
  u = (u + 0x7FFFu + ((u >> 16) & 1u)) >> 16;   // RNE
  return (unsigned short)u;
}
__device__ __forceinline__ float bf2f(unsigned short s) {
  unsigned int u = ((unsigned int)s) << 16;
  return __builtin_bit_cast(float, u);
}

__device__ __forceinline__ facc4 mfma_bf16(frag8 a, frag8 b, facc4 c) {
  return __builtin_amdgcn_mfma_f32_16x16x32_bf16(a, b, c, 0, 0, 0);
}

// ---------------------------------------------------------------------------
__global__ __launch_bounds__(256) void k_cvt_x(const float* __restrict__ in,
                                               unsigned short* __restrict__ out) {
  int i = (blockIdx.x * 256 + threadIdx.x) * 8;
  float4 a = *(const float4*)(in + i);
  float4 b = *(const float4*)(in + i + 4);
  frag8 r;
  r[0] = (short)f2bf(a.x); r[1] = (short)f2bf(a.y);
  r[2] = (short)f2bf(a.z); r[3] = (short)f2bf(a.w);
  r[4] = (short)f2bf(b.x); r[5] = (short)f2bf(b.y);
  r[6] = (short)f2bf(b.z); r[7] = (short)f2bf(b.w);
  *(frag8*)(out + i) = r;
}

// ---------------------------------------------------------------------------
__global__ __launch_bounds__(256) void k_prep_w(
    const float* __restrict__ wq, const float* __restrict__ wk,
    const float* __restrict__ wv, const float* __restrict__ wo,
    unsigned short* __restrict__ wqT, unsigned short* __restrict__ wkT,
    unsigned short* __restrict__ wvT, unsigned short* __restrict__ woT) {
  __shared__ unsigned short tile[64][65];
  const int bx = blockIdx.x;
  const float* src; unsigned short* dst;
  int ld_src, ld_dst, r0, c0;
  if (bx < 432) {
    int p = bx / 144, rem = bx % 144;
    int h = rem / 12, dt = rem % 12;
    src = (p == 0 ? wq : (p == 1 ? wk : wv)) + (size_t)h * 768 * 64;
    dst = (p == 0 ? wqT : (p == 1 ? wkT : wvT)) + (size_t)h * 64 * 768;
    ld_src = 64; ld_dst = 768; r0 = dt * 64; c0 = 0;
  } else {
    int t = bx - 432;
    src = wo; dst = woT;
    ld_src = 768; ld_dst = 768;
    r0 = (t / 12) * 64; c0 = (t % 12) * 64;
  }
  const int tid = threadIdx.x;
  const int lr = tid >> 2, lc0 = (tid & 3) * 16;
#pragma unroll
  for (int i = 0; i < 16; ++i)
    tile[lr][lc0 + i] = f2bf(src[(size_t)(r0 + lr) * ld_src + c0 + lc0 + i]);
  __syncthreads();
  const int oc = tid >> 2;
#pragma unroll
  for (int i = 0; i < 16; ++i)
    dst[(size_t)(c0 + oc) * ld_dst + r0 + lc0 + i] = tile[lc0 + i][oc];
}

// ---------------------------------------------------------------------------
__global__ __launch_bounds__(256) void k_qkv(
    const unsigned short* __restrict__ xb, const unsigned short* __restrict__ wT,
    const float* __restrict__ bq, const float* __restrict__ bk,
    const float* __restrict__ bv,
    unsigned short* __restrict__ qo, unsigned short* __restrict__ ko,
    unsigned short* __restrict__ vTo) {
  __shared__ __align__(16) unsigned short As[128 * 72];
  __shared__ __align__(16) unsigned short Bs[64 * 72];
  const int sb = blockIdx.x, ph = blockIdx.y;
  const int p = ph / 12, h = ph % 12;
  const int s0 = sb * 128;
  const int tid = threadIdx.x;
  const int w = tid >> 6, l = tid & 63;
  const int lg = l >> 4, li = l & 15;
  const int wm = w >> 1, wn = w & 1;
  const unsigned short* wTb = wT + (size_t)ph * 64 * 768;

  facc4 acc[4][2];
#pragma unroll
  for (int i = 0; i < 4; ++i)
#pragma unroll
    for (int j = 0; j < 2; ++j) acc[i][j] = (facc4){0.f, 0.f, 0.f, 0.f};

  const int rA = tid >> 3;
  const int c8 = (tid & 7) * 8;

  for (int k0 = 0; k0 < 768; k0 += 64) {
    frag8 av[4], bw[2];
#pragma unroll
    for (int i = 0; i < 4; ++i)
      av[i] = *(const frag8*)(xb + (size_t)(s0 + i * 32 + rA) * 768 + k0 + c8);
#pragma unroll
    for (int i = 0; i < 2; ++i)
      bw[i] = *(const frag8*)(wTb + (size_t)(i * 32 + rA) * 768 + k0 + c8);
#pragma unroll
    for (int i = 0; i < 4; ++i)
      *(frag8*)(&As[(i * 32 + rA) * 72 + c8]) = av[i];
#pragma unroll
    for (int i = 0; i < 2; ++i)
      *(frag8*)(&Bs[(i * 32 + rA) * 72 + c8]) = bw[i];
    __syncthreads();
#pragma unroll
    for (int kk = 0; kk < 2; ++kk) {
      const int ce = kk * 32 + lg * 8;
      frag8 a[4], b[2];
#pragma unroll
      for (int mf = 0; mf < 4; ++mf)
        a[mf] = *(const frag8*)(&As[(wm * 64 + mf * 16 + li) * 72 + ce]);
#pragma unroll
      for (int nf = 0; nf < 2; ++nf)
        b[nf] = *(const frag8*)(&Bs[(wn * 32 + nf * 16 + li) * 72 + ce]);
#pragma unroll
      for (int mf = 0; mf < 4; ++mf)
#pragma unroll
        for (int nf = 0; nf < 2; ++nf)
          acc[mf][nf] = mfma_bf16(a[mf], b[nf], acc[mf][nf]);
    }
    __syncthreads();
  }

  const float* bias = (p == 0 ? bq : (p == 1 ? bk : bv)) + h * 64;
  const float scale = (p == 0) ? 0.125f : 1.0f;
  float bvv[2];
#pragma unroll
  for (int nf = 0; nf < 2; ++nf) bvv[nf] = bias[wn * 32 + nf * 16 + li];
#pragma unroll
  for (int mf = 0; mf < 4; ++mf)
#pragma unroll
    for (int nf = 0; nf < 2; ++nf) {
      int e = wn * 32 + nf * 16 + li;
#pragma unroll
      for (int j = 0; j < 4; ++j) {
        int s = s0 + wm * 64 + mf * 16 + lg * 4 + j;
        unsigned short bf = f2bf((acc[mf][nf][j] + bvv[nf]) * scale);
        if (p == 0)      qo[((size_t)h * 4096 + s) * 64 + e] = bf;
        else if (p == 1) ko[((size_t)h * 4096 + s) * 64 + e] = bf;
        else             vTo[((size_t)h * 64 + e) * 4096 + s] = bf;
      }
    }
}

// ---------------------------------------------------------------------------
// Flash attention, split-K x2: grid (768, 2). blockIdx.x = h*64+qb (64 q rows),
// blockIdx.y = part (keys [part*2048, part*2048+2048)). 4 waves x 16 rows.
// Emits bf16 normalized partial o + f32 (m, l) per row.
__global__ __launch_bounds__(256) void k_attn(
    const unsigned short* __restrict__ q, const unsigned short* __restrict__ k,
    const unsigned short* __restrict__ vT,
    unsigned short* __restrict__ oP, float* __restrict__ mlP) {
  __shared__ __align__(16) unsigned short Pb[4][16 * 72];
  const int bid = blockIdx.x;
  const int part = blockIdx.y;
  const int h = bid >> 6, qb = bid & 63;
  const int s0 = qb * 64;
  const int tid = threadIdx.x;
  const int w = tid >> 6, l = tid & 63;
  const int lg = l >> 4, li = l & 15;
  unsigned short* P = &Pb[w][0];
  const unsigned short* Kh = k + (size_t)h * 4096 * 64;
  const unsigned short* Vh = vT + (size_t)h * 64 * 4096;

  const unsigned short* qrow = q + ((size_t)h * 4096 + s0 + w * 16 + li) * 64;
  frag8 qf0 = *(const frag8*)(qrow + lg * 8);
  frag8 qf1 = *(const frag8*)(qrow + 32 + lg * 8);

  float m[4], lsum[4];       // lsum is PER-LANE partial (reduced in epilogue)
  facc4 acc[4];
#pragma unroll
  for (int j = 0; j < 4; ++j) { m[j] = -1e30f; lsum[j] = 0.f; }
#pragma unroll
  for (int nf = 0; nf < 4; ++nf) acc[nf] = (facc4){0.f, 0.f, 0.f, 0.f};

  const int kt0 = part * 32, kt1 = kt0 + 32;
  for (int kt = kt0; kt < kt1; ++kt) {
    const int kbase = kt * 64;
    // S = Q K^T  (16 rows x 64 keys)
    facc4 sf[4];
#pragma unroll
    for (int cn = 0; cn < 4; ++cn) sf[cn] = (facc4){0.f, 0.f, 0.f, 0.f};
#pragma unroll
    for (int cn = 0; cn < 4; ++cn) {
      const unsigned short* kp = Kh + (size_t)(kbase + cn * 16 + li) * 64 + lg * 8;
      frag8 b0 = *(const frag8*)kp;
      frag8 b1 = *(const frag8*)(kp + 32);
      sf[cn] = mfma_bf16(qf0, b0, sf[cn]);
      sf[cn] = mfma_bf16(qf1, b1, sf[cn]);
    }
    // row max (16-lane groups)
    float tmax[4];
#pragma unroll
    for (int j = 0; j < 4; ++j)
      tmax[j] = fmaxf(fmaxf(sf[0][j], sf[1][j]), fmaxf(sf[2][j], sf[3][j]));
#pragma unroll
    for (int off = 1; off < 16; off <<= 1)
#pragma unroll
      for (int j = 0; j < 4; ++j)
        tmax[j] = fmaxf(tmax[j], __shfl_xor(tmax[j], off));
    // defer-max: rescale only when some row grew past m + THR
    bool need = false;
#pragma unroll
    for (int j = 0; j < 4; ++j) need |= (tmax[j] > m[j] + DEFER_THR);
    if (__any(need)) {
#pragma unroll
      for (int j = 0; j < 4; ++j) {
        float mn = fmaxf(m[j], tmax[j]);
        float corr = EXP2((m[j] - mn) * LOG2E);
        m[j] = mn;
        lsum[j] *= corr;
#pragma unroll
        for (int nf = 0; nf < 4; ++nf) acc[nf][j] *= corr;
      }
    }
    // P = exp(S-m) -> per-wave LDS; lsum accumulates per-lane (no reduce here)
#pragma unroll
    for (int cn = 0; cn < 4; ++cn)
#pragma unroll
      for (int j = 0; j < 4; ++j) {
        float pv = EXP2((sf[cn][j] - m[j]) * LOG2E);
        lsum[j] += pv;
        P[(lg * 4 + j) * 72 + cn * 16 + li] = f2bf(pv);
      }
    // ctx += P * V
#pragma unroll
    for (int pk = 0; pk < 2; ++pk) {
      frag8 pa = *(const frag8*)(&P[li * 72 + pk * 32 + lg * 8]);
#pragma unroll
      for (int nf = 0; nf < 4; ++nf) {
        const unsigned short* vp =
            Vh + (size_t)(nf * 16 + li) * 4096 + kbase + pk * 32 + lg * 8;
        frag8 vb = *(const frag8*)vp;
        acc[nf] = mfma_bf16(pa, vb, acc[nf]);
      }
    }
  }
  // epilogue: reduce lsum across the 16-lane row groups, emit partials
#pragma unroll
  for (int off = 1; off < 16; off <<= 1)
#pragma unroll
    for (int j = 0; j < 4; ++j)
      lsum[j] += __shfl_xor(lsum[j], off);
  const size_t base = ((size_t)(part * 12 + h) * 4096 + s0 + w * 16);
#pragma unroll
  for (int nf = 0; nf < 4; ++nf)
#pragma unroll
    for (int j = 0; j < 4; ++j) {
      int row = lg * 4 + j;
      oP[(base + row) * 64 + nf * 16 + li] = f2bf(acc[nf][j] / lsum[j]);
    }
  if (li == 0) {
#pragma unroll
    for (int j = 0; j < 4; ++j) {
      int row = lg * 4 + j;
      mlP[(base + row) * 2 + 0] = m[j];
      mlP[(base + row) * 2 + 1] = lsum[j];
    }
  }
}

// ---------------------------------------------------------------------------
// Combine split-K partials -> ctx bf16. grid 12288 x 256: 4 rows/block.
__global__ __launch_bounds__(256) void k_combine(
    const unsigned short* __restrict__ oP, const float* __restrict__ mlP,
    unsigned short* __restrict__ ctx) {
  const int tid = threadIdx.x;
  const int rg = blockIdx.x * 4 + (tid >> 6);    // 0..49151 = h*4096+s
  const int e = tid & 63;
  const int h = rg >> 12, s = rg & 4095;
  const size_t r0 = (size_t)(0 * 12 + h) * 4096 + s;
  const size_t r1 = (size_t)(1 * 12 + h) * 4096 + s;
  float m0 = mlP[r0 * 2], l0 = mlP[r0 * 2 + 1];
  float m1 = mlP[r1 * 2], l1 = mlP[r1 * 2 + 1];
  float M = fmaxf(m0, m1);
  float w0 = l0 * EXP2((m0 - M) * LOG2E);
  float w1 = l1 * EXP2((m1 - M) * LOG2E);
  float inv = 1.f / (w0 + w1);
  float o = (w0 * bf2f(oP[r0 * 64 + e]) + w1 * bf2f(oP[r1 * 64 + e])) * inv;
  ctx[(size_t)s * 768 + h * 64 + e] = f2bf(o);
}

// ---------------------------------------------------------------------------
__global__ __launch_bounds__(256) void k_proj(
    const unsigned short* __restrict__ ctx, const unsigned short* __restrict__ woT,
    const float* __restrict__ bo, float* __restrict__ out) {
  __shared__ __align__(16) unsigned short As[64 * 72];
  __shared__ __align__(16) unsigned short Bs[64 * 72];
  const int s0 = blockIdx.x * 64, j0 = blockIdx.y * 64;
  const int tid = threadIdx.x;
  const int w = tid >> 6, l = tid & 63;
  const int lg = l >> 4, li = l & 15;
  const int wm = w >> 1, wn = w & 1;
  facc4 acc[2][2];
#pragma unroll
  for (int i = 0; i < 2; ++i)
#pragma unroll
    for (int j = 0; j < 2; ++j) acc[i][j] = (facc4){0.f, 0.f, 0.f, 0.f};

  const int rA = tid >> 3;
  const int c8 = (tid & 7) * 8;

  for (int k0 = 0; k0 < 768; k0 += 64) {
    frag8 av[2], bw[2];
#pragma unroll
    for (int i = 0; i < 2; ++i) {
      av[i] = *(const frag8*)(ctx + (size_t)(s0 + i * 32 + rA) * 768 + k0 + c8);
      bw[i] = *(const frag8*)(woT + (size_t)(j0 + i * 32 + rA) * 768 + k0 + c8);
    }
#pragma unroll
    for (int i = 0; i < 2; ++i) {
      *(frag8*)(&As[(i * 32 + rA) * 72 + c8]) = av[i];
      *(frag8*)(&Bs[(i * 32 + rA) * 72 + c8]) = bw[i];
    }
    __syncthreads();
#pragma unroll
    for (int kk = 0; kk < 2; ++kk) {
      const int ce = kk * 32 + lg * 8;
      frag8 a[2], b[2];
#pragma unroll
      for (int mf = 0; mf < 2; ++mf)
        a[mf] = *(const frag8*)(&As[(wm * 32 + mf * 16 + li) * 72 + ce]);
#pragma unroll
      for (int nf = 0; nf < 2; ++nf)
        b[nf] = *(const frag8*)(&Bs[(wn * 32 + nf * 16 + li) * 72 + ce]);
#pragma unroll
      for (int mf = 0; mf < 2; ++mf)
#pragma unroll
        for (int nf = 0; nf < 2; ++nf)
          acc[mf][nf] = mfma_bf16(a[mf], b[nf], acc[mf][nf]);
    }
    __syncthreads();
  }
#pragma unroll
  for (int nf = 0; nf < 2; ++nf) {
    int jc = j0 + wn * 32 + nf * 16 + li;
    float bb = bo[jc];
#pragma unroll
    for (int mf = 0; mf < 2; ++mf)
#pragma unroll
      for (int j = 0; j < 4; ++j) {
        int s = s0 + wm * 32 + mf * 16 + lg * 4 + j;
        out[(size_t)s * 768 + jc] = acc[mf][nf][j] + bb;   // F32 STORE
      }
  }
}

// ---------------------------------------------------------------------------
extern "C" void kernel_launch(void* const* d_in, const int* in_sizes, int n_in,
                              void* d_out, int out_size, void* d_ws, size_t ws_size,
                              hipStream_t stream) {
  const float* x  = (const float*)d_in[0];
  const float* wq = (const float*)d_in[1];
  const float* bq = (const float*)d_in[2];
  const float* wk = (const float*)d_in[3];
  const float* bk = (const float*)d_in[4];
  const float* wv = (const float*)d_in[5];
  const float* bv = (const float*)d_in[6];
  const float* wo = (const float*)d_in[7];
  const float* bo = (const float*)d_in[8];
  float* out = (float*)d_out;   // F32 output (proven)

  char* ws = (char*)d_ws;
  unsigned short* xb  = (unsigned short*)(ws);
  unsigned short* wT  = (unsigned short*)(ws + 6291456);
  unsigned short* woT = (unsigned short*)(ws + 9830400);
  unsigned short* qd  = (unsigned short*)(ws + 11010048);
  unsigned short* kd  = (unsigned short*)(ws + 17301504);
  unsigned short* vTd = (unsigned short*)(ws + 23592960);
  unsigned short* ctx = (unsigned short*)(ws + 29884416);
  unsigned short* oP  = (unsigned short*)(ws + 36175872);
  float*          mlP = (float*)(ws + 48758784);

  k_cvt_x<<<1536, 256, 0, stream>>>(x, xb);
  k_prep_w<<<576, 256, 0, stream>>>(wq, wk, wv, wo,
                                    wT, wT + 589824, wT + 1179648, woT);
  k_qkv<<<dim3(32, 36), 256, 0, stream>>>(xb, wT, bq, bk, bv, qd, kd, vTd);
  k_attn<<<dim3(768, 2), 256, 0, stream>>>(qd, kd, vTd, oP, mlP);
  k_combine<<<12288, 256, 0, stream>>>(oP, mlP, ctx);
  k_proj<<<dim3(64, 12), 256, 0, stream>>>(ctx, woT, bo, out);
}

// Round 7
// 195.709 us; speedup vs baseline: 2.0653x; 2.0653x over previous
//
#include <hip/hip_runtime.h>

// ---------------------------------------------------------------------------
// MultiHeadedAttention fused pipeline for MI355X (gfx950), bf16 MFMA.
// B=1, S=4096, D=768, H=12, DH=64.
// Round 7: k_attn TA-gather fix — K/V tiles staged to LDS via coalesced
// global_load_lds (shared by all 4 waves, was 4x redundant 16-line gathers),
// double-buffered 2-phase loop, XOR-swizzled (both-sides involution).
// Workspace layout unchanged from round 6 (49545216 bytes).
// ---------------------------------------------------------------------------

using frag8 = __attribute__((ext_vector_type(8))) short;   // 8 x bf16 (4 VGPRs)
using facc4 = __attribute__((ext_vector_type(4))) float;   // MFMA accumulator

#define LOG2E 1.4426950408889634f
#define DEFER_THR 8.0f
#define SWZ16(r, b) ((b) ^ (((r) & 7) << 4))

#if defined(__has_builtin)
#  if __has_builtin(__builtin_amdgcn_exp2f)
#    define EXP2(x) __builtin_amdgcn_exp2f(x)
#  else
#    define EXP2(x) exp2f(x)
#  endif
#else
#  define EXP2(x) exp2f(x)
#endif

__device__ __forceinline__ unsigned short f2bf(float f) {
  unsigned int u = __builtin_bit_cast(unsigned int, f);
  u = (u + 0x7FFFu + ((u >> 16) & 1u)) >> 16;   // RNE
  return (unsigned short)u;
}
__device__ __forceinline__ float bf2f(unsigned short s) {
  unsigned int u = ((unsigned int)s) << 16;
  return __builtin_bit_cast(float, u);
}

__device__ __forceinline__ facc4 mfma_bf16(frag8 a, frag8 b, facc4 c) {
  return __builtin_amdgcn_mfma_f32_16x16x32_bf16(a, b, c, 0, 0, 0);
}

__device__ __forceinline__ void gld_lds16(const void* g, void* l) {
  auto gp = (const __attribute__((address_space(1))) unsigned int*)g;
  auto lp = (__attribute__((address_space(3))) unsigned int*)l;
  __builtin_amdgcn_global_load_lds(gp, lp, 16, 0, 0);
}

// ---------------------------------------------------------------------------
__global__ __launch_bounds__(256) void k_cvt_x(const float* __restrict__ in,
                                               unsigned short* __restrict__ out) {
  int i = (blockIdx.x * 256 + threadIdx.x) * 8;
  float4 a = *(const float4*)(in + i);
  float4 b = *(const float4*)(in + i + 4);
  frag8 r;
  r[0] = (short)f2bf(a.x); r[1] = (short)f2bf(a.y);
  r[2] = (short)f2bf(a.z); r[3] = (short)f2bf(a.w);
  r[4] = (short)f2bf(b.x); r[5] = (short)f2bf(b.y);
  r[6] = (short)f2bf(b.z); r[7] = (short)f2bf(b.w);
  *(frag8*)(out + i) = r;
}

// ---------------------------------------------------------------------------
__global__ __launch_bounds__(256) void k_prep_w(
    const float* __restrict__ wq, const float* __restrict__ wk,
    const float* __restrict__ wv, const float* __restrict__ wo,
    unsigned short* __restrict__ wqT, unsigned short* __restrict__ wkT,
    unsigned short* __restrict__ wvT, unsigned short* __restrict__ woT) {
  __shared__ unsigned short tile[64][65];
  const int bx = blockIdx.x;
  const float* src; unsigned short* dst;
  int ld_src, ld_dst, r0, c0;
  if (bx < 432) {
    int p = bx / 144, rem = bx % 144;
    int h = rem / 12, dt = rem % 12;
    src = (p == 0 ? wq : (p == 1 ? wk : wv)) + (size_t)h * 768 * 64;
    dst = (p == 0 ? wqT : (p == 1 ? wkT : wvT)) + (size_t)h * 64 * 768;
    ld_src = 64; ld_dst = 768; r0 = dt * 64; c0 = 0;
  } else {
    int t = bx - 432;
    src = wo; dst = woT;
    ld_src = 768; ld_dst = 768;
    r0 = (t / 12) * 64; c0 = (t % 12) * 64;
  }
  const int tid = threadIdx.x;
  const int lr = tid >> 2, lc0 = (tid & 3) * 16;
#pragma unroll
  for (int i = 0; i < 16; ++i)
    tile[lr][lc0 + i] = f2bf(src[(size_t)(r0 + lr) * ld_src + c0 + lc0 + i]);
  __syncthreads();
  const int oc = tid >> 2;
#pragma unroll
  for (int i = 0; i < 16; ++i)
    dst[(size_t)(c0 + oc) * ld_dst + r0 + lc0 + i] = tile[lc0 + i][oc];
}

// ---------------------------------------------------------------------------
__global__ __launch_bounds__(256) void k_qkv(
    const unsigned short* __restrict__ xb, const unsigned short* __restrict__ wT,
    const float* __restrict__ bq, const float* __restrict__ bk,
    const float* __restrict__ bv,
    unsigned short* __restrict__ qo, unsigned short* __restrict__ ko,
    unsigned short* __restrict__ vTo) {
  __shared__ __align__(16) unsigned short As[128 * 72];
  __shared__ __align__(16) unsigned short Bs[64 * 72];
  const int sb = blockIdx.x, ph = blockIdx.y;
  const int p = ph / 12, h = ph % 12;
  const int s0 = sb * 128;
  const int tid = threadIdx.x;
  const int w = tid >> 6, l = tid & 63;
  const int lg = l >> 4, li = l & 15;
  const int wm = w >> 1, wn = w & 1;
  const unsigned short* wTb = wT + (size_t)ph * 64 * 768;

  facc4 acc[4][2];
#pragma unroll
  for (int i = 0; i < 4; ++i)
#pragma unroll
    for (int j = 0; j < 2; ++j) acc[i][j] = (facc4){0.f, 0.f, 0.f, 0.f};

  const int rA = tid >> 3;
  const int c8 = (tid & 7) * 8;

  for (int k0 = 0; k0 < 768; k0 += 64) {
    frag8 av[4], bw[2];
#pragma unroll
    for (int i = 0; i < 4; ++i)
      av[i] = *(const frag8*)(xb + (size_t)(s0 + i * 32 + rA) * 768 + k0 + c8);
#pragma unroll
    for (int i = 0; i < 2; ++i)
      bw[i] = *(const frag8*)(wTb + (size_t)(i * 32 + rA) * 768 + k0 + c8);
#pragma unroll
    for (int i = 0; i < 4; ++i)
      *(frag8*)(&As[(i * 32 + rA) * 72 + c8]) = av[i];
#pragma unroll
    for (int i = 0; i < 2; ++i)
      *(frag8*)(&Bs[(i * 32 + rA) * 72 + c8]) = bw[i];
    __syncthreads();
#pragma unroll
    for (int kk = 0; kk < 2; ++kk) {
      const int ce = kk * 32 + lg * 8;
      frag8 a[4], b[2];
#pragma unroll
      for (int mf = 0; mf < 4; ++mf)
        a[mf] = *(const frag8*)(&As[(wm * 64 + mf * 16 + li) * 72 + ce]);
#pragma unroll
      for (int nf = 0; nf < 2; ++nf)
        b[nf] = *(const frag8*)(&Bs[(wn * 32 + nf * 16 + li) * 72 + ce]);
#pragma unroll
      for (int mf = 0; mf < 4; ++mf)
#pragma unroll
        for (int nf = 0; nf < 2; ++nf)
          acc[mf][nf] = mfma_bf16(a[mf], b[nf], acc[mf][nf]);
    }
    __syncthreads();
  }

  const float* bias = (p == 0 ? bq : (p == 1 ? bk : bv)) + h * 64;
  const float scale = (p == 0) ? 0.125f : 1.0f;
  float bvv[2];
#pragma unroll
  for (int nf = 0; nf < 2; ++nf) bvv[nf] = bias[wn * 32 + nf * 16 + li];
#pragma unroll
  for (int mf = 0; mf < 4; ++mf)
#pragma unroll
    for (int nf = 0; nf < 2; ++nf) {
      int e = wn * 32 + nf * 16 + li;
#pragma unroll
      for (int j = 0; j < 4; ++j) {
        int s = s0 + wm * 64 + mf * 16 + lg * 4 + j;
        unsigned short bf = f2bf((acc[mf][nf][j] + bvv[nf]) * scale);
        if (p == 0)      qo[((size_t)h * 4096 + s) * 64 + e] = bf;
        else if (p == 1) ko[((size_t)h * 4096 + s) * 64 + e] = bf;
        else             vTo[((size_t)h * 64 + e) * 4096 + s] = bf;
      }
    }
}

// ---------------------------------------------------------------------------
// Flash attention v3: split-K x2, LDS-staged K/V (double-buffered, swizzled).
// grid (768, 2); 4 waves x 16 q-rows; K-tile 64x64, V^T-tile 64x64.
// LDS: K 2x8KB + V 2x8KB + P 4x2KB = 40KB -> 4 blocks/CU.
__global__ __launch_bounds__(256) void k_attn(
    const unsigned short* __restrict__ q, const unsigned short* __restrict__ k,
    const unsigned short* __restrict__ vT,
    unsigned short* __restrict__ oP, float* __restrict__ mlP) {
  __shared__ __align__(16) char Kb[2][8192];   // [key r][128B], swizzled
  __shared__ __align__(16) char Vb[2][8192];   // [dh r][128B of keys], swizzled
  __shared__ __align__(16) char Pb[4][2048];   // per-wave P [qrow][128B], swz
  const int bid = blockIdx.x;
  const int part = blockIdx.y;
  const int h = bid >> 6, qb = bid & 63;
  const int s0 = qb * 64;
  const int tid = threadIdx.x;
  const int w = tid >> 6, l = tid & 63;
  const int lg = l >> 4, li = l & 15;
  char* P = Pb[w];
  const unsigned short* Kh = k + (size_t)h * 4096 * 64;
  const unsigned short* Vh = vT + (size_t)h * 64 * 4096;

  // staging indices: thread covers (row r, 16B granule b), source pre-swizzled
  const int rS = tid >> 3;            // 0..31 (+32 on second pass)
  const int bS = (tid & 7) * 16;      // byte granule within 128B row

  const unsigned short* qrow = q + ((size_t)h * 4096 + s0 + w * 16 + li) * 64;
  frag8 qf0 = *(const frag8*)(qrow + lg * 8);
  frag8 qf1 = *(const frag8*)(qrow + 32 + lg * 8);

  float m[4], lsum[4];
  facc4 acc[4];
#pragma unroll
  for (int j = 0; j < 4; ++j) { m[j] = -1e30f; lsum[j] = 0.f; }
#pragma unroll
  for (int nf = 0; nf < 4; ++nf) acc[nf] = (facc4){0.f, 0.f, 0.f, 0.f};

  const int kb0 = part * 2048;

  // prologue: stage tile 0 into buf 0
#pragma unroll
  for (int i = 0; i < 2; ++i) {
    int r = i * 32 + rS;
    int sb = SWZ16(r, bS);
    gld_lds16((const char*)(Kh + (size_t)(kb0 + r) * 64) + sb,
              Kb[0] + i * 4096 + w * 1024);
    gld_lds16((const char*)(Vh + (size_t)r * 4096 + kb0) + sb,
              Vb[0] + i * 4096 + w * 1024);
  }
  __syncthreads();

  int cur = 0;
  for (int kt = 0; kt < 32; ++kt) {
    // issue next-tile staging (overlaps compute below; drained at barrier)
    if (kt < 31) {
      const int kbn = kb0 + (kt + 1) * 64;
#pragma unroll
      for (int i = 0; i < 2; ++i) {
        int r = i * 32 + rS;
        int sb = SWZ16(r, bS);
        gld_lds16((const char*)(Kh + (size_t)(kbn + r) * 64) + sb,
                  Kb[cur ^ 1] + i * 4096 + w * 1024);
        gld_lds16((const char*)(Vh + (size_t)r * 4096 + kbn) + sb,
                  Vb[cur ^ 1] + i * 4096 + w * 1024);
      }
    }
    const char* Kc = Kb[cur];
    const char* Vc = Vb[cur];

    // S = Q K^T  (16 rows x 64 keys), K frags from swizzled LDS
    facc4 sf[4];
#pragma unroll
    for (int cn = 0; cn < 4; ++cn) sf[cn] = (facc4){0.f, 0.f, 0.f, 0.f};
#pragma unroll
    for (int cn = 0; cn < 4; ++cn) {
      int r = cn * 16 + li;
      frag8 b0 = *(const frag8*)(Kc + r * 128 + SWZ16(r, lg * 16));
      frag8 b1 = *(const frag8*)(Kc + r * 128 + SWZ16(r, 64 + lg * 16));
      sf[cn] = mfma_bf16(qf0, b0, sf[cn]);
      sf[cn] = mfma_bf16(qf1, b1, sf[cn]);
    }
    // row max (16-lane groups)
    float tmax[4];
#pragma unroll
    for (int j = 0; j < 4; ++j)
      tmax[j] = fmaxf(fmaxf(sf[0][j], sf[1][j]), fmaxf(sf[2][j], sf[3][j]));
#pragma unroll
    for (int off = 1; off < 16; off <<= 1)
#pragma unroll
      for (int j = 0; j < 4; ++j)
        tmax[j] = fmaxf(tmax[j], __shfl_xor(tmax[j], off));
    // defer-max rescale
    bool need = false;
#pragma unroll
    for (int j = 0; j < 4; ++j) need |= (tmax[j] > m[j] + DEFER_THR);
    if (__any(need)) {
#pragma unroll
      for (int j = 0; j < 4; ++j) {
        float mn = fmaxf(m[j], tmax[j]);
        float corr = EXP2((m[j] - mn) * LOG2E);
        m[j] = mn;
        lsum[j] *= corr;
#pragma unroll
        for (int nf = 0; nf < 4; ++nf) acc[nf][j] *= corr;
      }
    }
    // P = exp(S-m) -> per-wave swizzled LDS; per-lane lsum
#pragma unroll
    for (int cn = 0; cn < 4; ++cn)
#pragma unroll
      for (int j = 0; j < 4; ++j) {
        float pv = EXP2((sf[cn][j] - m[j]) * LOG2E);
        lsum[j] += pv;
        int r = lg * 4 + j;
        *(unsigned short*)(P + r * 128 + SWZ16(r, (cn * 16 + li) * 2)) = f2bf(pv);
      }
    // ctx += P * V  (A-frags from swizzled P, B-frags from swizzled V LDS)
#pragma unroll
    for (int pk = 0; pk < 2; ++pk) {
      frag8 pa = *(const frag8*)(P + li * 128 + SWZ16(li, pk * 64 + lg * 16));
#pragma unroll
      for (int nf = 0; nf < 4; ++nf) {
        int rv = nf * 16 + li;
        frag8 vb = *(const frag8*)(Vc + rv * 128 + SWZ16(rv, pk * 64 + lg * 16));
        acc[nf] = mfma_bf16(pa, vb, acc[nf]);
      }
    }
    __syncthreads();   // drains vmcnt(0) (incl. prefetch) + protects buffers
    cur ^= 1;
  }
  // epilogue: reduce lsum across 16-lane groups, emit partials
#pragma unroll
  for (int off = 1; off < 16; off <<= 1)
#pragma unroll
    for (int j = 0; j < 4; ++j)
      lsum[j] += __shfl_xor(lsum[j], off);
  const size_t base = ((size_t)(part * 12 + h) * 4096 + s0 + w * 16);
#pragma unroll
  for (int nf = 0; nf < 4; ++nf)
#pragma unroll
    for (int j = 0; j < 4; ++j) {
      int row = lg * 4 + j;
      oP[(base + row) * 64 + nf * 16 + li] = f2bf(acc[nf][j] / lsum[j]);
    }
  if (li == 0) {
#pragma unroll
    for (int j = 0; j < 4; ++j) {
      int row = lg * 4 + j;
      mlP[(base + row) * 2 + 0] = m[j];
      mlP[(base + row) * 2 + 1] = lsum[j];
    }
  }
}

// ---------------------------------------------------------------------------
// Combine split-K partials -> ctx bf16. grid 12288 x 256: 4 rows/block.
__global__ __launch_bounds__(256) void k_combine(
    const unsigned short* __restrict__ oP, const float* __restrict__ mlP,
    unsigned short* __restrict__ ctx) {
  const int tid = threadIdx.x;
  const int rg = blockIdx.x * 4 + (tid >> 6);
  const int e = tid & 63;
  const int h = rg >> 12, s = rg & 4095;
  const size_t r0 = (size_t)h * 4096 + s;
  const size_t r1 = (size_t)(12 + h) * 4096 + s;
  float m0 = mlP[r0 * 2], l0 = mlP[r0 * 2 + 1];
  float m1 = mlP[r1 * 2], l1 = mlP[r1 * 2 + 1];
  float M = fmaxf(m0, m1);
  float w0 = l0 * EXP2((m0 - M) * LOG2E);
  float w1 = l1 * EXP2((m1 - M) * LOG2E);
  float inv = 1.f / (w0 + w1);
  float o = (w0 * bf2f(oP[r0 * 64 + e]) + w1 * bf2f(oP[r1 * 64 + e])) * inv;
  ctx[(size_t)s * 768 + h * 64 + e] = f2bf(o);
}

// ---------------------------------------------------------------------------
__global__ __launch_bounds__(256) void k_proj(
    const unsigned short* __restrict__ ctx, const unsigned short* __restrict__ woT,
    const float* __restrict__ bo, float* __restrict__ out) {
  __shared__ __align__(16) unsigned short As[64 * 72];
  __shared__ __align__(16) unsigned short Bs[64 * 72];
  const int s0 = blockIdx.x * 64, j0 = blockIdx.y * 64;
  const int tid = threadIdx.x;
  const int w = tid >> 6, l = tid & 63;
  const int lg = l >> 4, li = l & 15;
  const int wm = w >> 1, wn = w & 1;
  facc4 acc[2][2];
#pragma unroll
  for (int i = 0; i < 2; ++i)
#pragma unroll
    for (int j = 0; j < 2; ++j) acc[i][j] = (facc4){0.f, 0.f, 0.f, 0.f};

  const int rA = tid >> 3;
  const int c8 = (tid & 7) * 8;

  for (int k0 = 0; k0 < 768; k0 += 64) {
    frag8 av[2], bw[2];
#pragma unroll
    for (int i = 0; i < 2; ++i) {
      av[i] = *(const frag8*)(ctx + (size_t)(s0 + i * 32 + rA) * 768 + k0 + c8);
      bw[i] = *(const frag8*)(woT + (size_t)(j0 + i * 32 + rA) * 768 + k0 + c8);
    }
#pragma unroll
    for (int i = 0; i < 2; ++i) {
      *(frag8*)(&As[(i * 32 + rA) * 72 + c8]) = av[i];
      *(frag8*)(&Bs[(i * 32 + rA) * 72 + c8]) = bw[i];
    }
    __syncthreads();
#pragma unroll
    for (int kk = 0; kk < 2; ++kk) {
      const int ce = kk * 32 + lg * 8;
      frag8 a[2], b[2];
#pragma unroll
      for (int mf = 0; mf < 2; ++mf)
        a[mf] = *(const frag8*)(&As[(wm * 32 + mf * 16 + li) * 72 + ce]);
#pragma unroll
      for (int nf = 0; nf < 2; ++nf)
        b[nf] = *(const frag8*)(&Bs[(wn * 32 + nf * 16 + li) * 72 + ce]);
#pragma unroll
      for (int mf = 0; mf < 2; ++mf)
#pragma unroll
        for (int nf = 0; nf < 2; ++nf)
          acc[mf][nf] = mfma_bf16(a[mf], b[nf], acc[mf][nf]);
    }
    __syncthreads();
  }
#pragma unroll
  for (int nf = 0; nf < 2; ++nf) {
    int jc = j0 + wn * 32 + nf * 16 + li;
    float bb = bo[jc];
#pragma unroll
    for (int mf = 0; mf < 2; ++mf)
#pragma unroll
      for (int j = 0; j < 4; ++j) {
        int s = s0 + wm * 32 + mf * 16 + lg * 4 + j;
        out[(size_t)s * 768 + jc] = acc[mf][nf][j] + bb;   // F32 STORE
      }
  }
}

// ---------------------------------------------------------------------------
extern "C" void kernel_launch(void* const* d_in, const int* in_sizes, int n_in,
                              void* d_out, int out_size, void* d_ws, size_t ws_size,
                              hipStream_t stream) {
  const float* x  = (const float*)d_in[0];
  const float* wq = (const float*)d_in[1];
  const float* bq = (const float*)d_in[2];
  const float* wk = (const float*)d_in[3];
  const float* bk = (const float*)d_in[4];
  const float* wv = (const float*)d_in[5];
  const float* bv = (const float*)d_in[6];
  const float* wo = (const float*)d_in[7];
  const float* bo = (const float*)d_in[8];
  float* out = (float*)d_out;   // F32 output (proven)

  char* ws = (char*)d_ws;
  unsigned short* xb  = (unsigned short*)(ws);
  unsigned short* wT  = (unsigned short*)(ws + 6291456);
  unsigned short* woT = (unsigned short*)(ws + 9830400);
  unsigned short* qd  = (unsigned short*)(ws + 11010048);
  unsigned short* kd  = (unsigned short*)(ws + 17301504);
  unsigned short* vTd = (unsigned short*)(ws + 23592960);
  unsigned short* ctx = (unsigned short*)(ws + 29884416);
  unsigned short* oP  = (unsigned short*)(ws + 36175872);
  float*          mlP = (float*)(ws + 48758784);

  k_cvt_x<<<1536, 256, 0, stream>>>(x, xb);
  k_prep_w<<<576, 256, 0, stream>>>(wq, wk, wv, wo,
                                    wT, wT + 589824, wT + 1179648, woT);
  k_qkv<<<dim3(32, 36), 256, 0, stream>>>(xb, wT, bq, bk, bv, qd, kd, vTd);
  k_attn<<<dim3(768, 2), 256, 0, stream>>>(qd, kd, vTd, oP, mlP);
  k_combine<<<12288, 256, 0, stream>>>(oP, mlP, ctx);
  k_proj<<<dim3(64, 12), 256, 0, stream>>>(ctx, woT, bo, out);
}

// Round 8
// 156.696 us; speedup vs baseline: 2.5794x; 1.2490x over previous
//
#include <hip/hip_runtime.h>

// ---------------------------------------------------------------------------
// MultiHeadedAttention fused pipeline for MI355X (gfx950), bf16 MFMA.
// B=1, S=4096, D=768, H=12, DH=64.
// Round 8: k_attn swapped-QK^T in-register softmax:
//   - mfma(K,Q) -> lane holds 16 scores of its own q-row (col=q=li)
//   - K-fragment row permutation kappa = base[cn]+8*(li>>2)+(li&3) relabels
//     keys so P->PV A-frags are lane-local: 8x v_cvt_pk_bf16_f32, no LDS
//     bounce, no shuffles (V layout unaffected by key relabeling)
//   - q pre-scaled by 0.125*LOG2E at k_qkv -> exp2-direct softmax
//   - LDS 40KB->32KB (Pb removed) -> 5 blocks/CU
// Workspace layout unchanged (49545216 bytes).
// ---------------------------------------------------------------------------

using frag8 = __attribute__((ext_vector_type(8))) short;   // 8 x bf16 (4 VGPRs)
using facc4 = __attribute__((ext_vector_type(4))) float;   // MFMA accumulator
using uint4v = __attribute__((ext_vector_type(4))) unsigned int;

#define LOG2E 1.4426950408889634f
#define THR_LOG2 11.5415603f      // 8 * LOG2E (defer-max threshold, log2 units)
#define SWZ16(r, b) ((b) ^ (((r) & 7) << 4))

#if defined(__has_builtin)
#  if __has_builtin(__builtin_amdgcn_exp2f)
#    define EXP2(x) __builtin_amdgcn_exp2f(x)
#  else
#    define EXP2(x) exp2f(x)
#  endif
#else
#  define EXP2(x) exp2f(x)
#endif

__device__ __forceinline__ unsigned short f2bf(float f) {
  unsigned int u = __builtin_bit_cast(unsigned int, f);
  u = (u + 0x7FFFu + ((u >> 16) & 1u)) >> 16;   // RNE
  return (unsigned short)u;
}
__device__ __forceinline__ float bf2f(unsigned short s) {
  unsigned int u = ((unsigned int)s) << 16;
  return __builtin_bit_cast(float, u);
}
__device__ __forceinline__ unsigned cvt_pk_bf16(float lo, float hi) {
  unsigned r;
  asm("v_cvt_pk_bf16_f32 %0, %1, %2" : "=v"(r) : "v"(lo), "v"(hi));
  return r;
}

__device__ __forceinline__ facc4 mfma_bf16(frag8 a, frag8 b, facc4 c) {
  return __builtin_amdgcn_mfma_f32_16x16x32_bf16(a, b, c, 0, 0, 0);
}

__device__ __forceinline__ void gld_lds16(const void* g, void* l) {
  auto gp = (const __attribute__((address_space(1))) unsigned int*)g;
  auto lp = (__attribute__((address_space(3))) unsigned int*)l;
  __builtin_amdgcn_global_load_lds(gp, lp, 16, 0, 0);
}

// ---------------------------------------------------------------------------
__global__ __launch_bounds__(256) void k_cvt_x(const float* __restrict__ in,
                                               unsigned short* __restrict__ out) {
  int i = (blockIdx.x * 256 + threadIdx.x) * 8;
  float4 a = *(const float4*)(in + i);
  float4 b = *(const float4*)(in + i + 4);
  frag8 r;
  r[0] = (short)f2bf(a.x); r[1] = (short)f2bf(a.y);
  r[2] = (short)f2bf(a.z); r[3] = (short)f2bf(a.w);
  r[4] = (short)f2bf(b.x); r[5] = (short)f2bf(b.y);
  r[6] = (short)f2bf(b.z); r[7] = (short)f2bf(b.w);
  *(frag8*)(out + i) = r;
}

// ---------------------------------------------------------------------------
__global__ __launch_bounds__(256) void k_prep_w(
    const float* __restrict__ wq, const float* __restrict__ wk,
    const float* __restrict__ wv, const float* __restrict__ wo,
    unsigned short* __restrict__ wqT, unsigned short* __restrict__ wkT,
    unsigned short* __restrict__ wvT, unsigned short* __restrict__ woT) {
  __shared__ unsigned short tile[64][65];
  const int bx = blockIdx.x;
  const float* src; unsigned short* dst;
  int ld_src, ld_dst, r0, c0;
  if (bx < 432) {
    int p = bx / 144, rem = bx % 144;
    int h = rem / 12, dt = rem % 12;
    src = (p == 0 ? wq : (p == 1 ? wk : wv)) + (size_t)h * 768 * 64;
    dst = (p == 0 ? wqT : (p == 1 ? wkT : wvT)) + (size_t)h * 64 * 768;
    ld_src = 64; ld_dst = 768; r0 = dt * 64; c0 = 0;
  } else {
    int t = bx - 432;
    src = wo; dst = woT;
    ld_src = 768; ld_dst = 768;
    r0 = (t / 12) * 64; c0 = (t % 12) * 64;
  }
  const int tid = threadIdx.x;
  const int lr = tid >> 2, lc0 = (tid & 3) * 16;
#pragma unroll
  for (int i = 0; i < 16; ++i)
    tile[lr][lc0 + i] = f2bf(src[(size_t)(r0 + lr) * ld_src + c0 + lc0 + i]);
  __syncthreads();
  const int oc = tid >> 2;
#pragma unroll
  for (int i = 0; i < 16; ++i)
    dst[(size_t)(c0 + oc) * ld_dst + r0 + lc0 + i] = tile[lc0 + i][oc];
}

// ---------------------------------------------------------------------------
__global__ __launch_bounds__(256) void k_qkv(
    const unsigned short* __restrict__ xb, const unsigned short* __restrict__ wT,
    const float* __restrict__ bq, const float* __restrict__ bk,
    const float* __restrict__ bv,
    unsigned short* __restrict__ qo, unsigned short* __restrict__ ko,
    unsigned short* __restrict__ vTo) {
  __shared__ __align__(16) unsigned short As[128 * 72];
  __shared__ __align__(16) unsigned short Bs[64 * 72];
  const int sb = blockIdx.x, ph = blockIdx.y;
  const int p = ph / 12, h = ph % 12;
  const int s0 = sb * 128;
  const int tid = threadIdx.x;
  const int w = tid >> 6, l = tid & 63;
  const int lg = l >> 4, li = l & 15;
  const int wm = w >> 1, wn = w & 1;
  const unsigned short* wTb = wT + (size_t)ph * 64 * 768;

  facc4 acc[4][2];
#pragma unroll
  for (int i = 0; i < 4; ++i)
#pragma unroll
    for (int j = 0; j < 2; ++j) acc[i][j] = (facc4){0.f, 0.f, 0.f, 0.f};

  const int rA = tid >> 3;
  const int c8 = (tid & 7) * 8;

  for (int k0 = 0; k0 < 768; k0 += 64) {
    frag8 av[4], bw[2];
#pragma unroll
    for (int i = 0; i < 4; ++i)
      av[i] = *(const frag8*)(xb + (size_t)(s0 + i * 32 + rA) * 768 + k0 + c8);
#pragma unroll
    for (int i = 0; i < 2; ++i)
      bw[i] = *(const frag8*)(wTb + (size_t)(i * 32 + rA) * 768 + k0 + c8);
#pragma unroll
    for (int i = 0; i < 4; ++i)
      *(frag8*)(&As[(i * 32 + rA) * 72 + c8]) = av[i];
#pragma unroll
    for (int i = 0; i < 2; ++i)
      *(frag8*)(&Bs[(i * 32 + rA) * 72 + c8]) = bw[i];
    __syncthreads();
#pragma unroll
    for (int kk = 0; kk < 2; ++kk) {
      const int ce = kk * 32 + lg * 8;
      frag8 a[4], b[2];
#pragma unroll
      for (int mf = 0; mf < 4; ++mf)
        a[mf] = *(const frag8*)(&As[(wm * 64 + mf * 16 + li) * 72 + ce]);
#pragma unroll
      for (int nf = 0; nf < 2; ++nf)
        b[nf] = *(const frag8*)(&Bs[(wn * 32 + nf * 16 + li) * 72 + ce]);
#pragma unroll
      for (int mf = 0; mf < 4; ++mf)
#pragma unroll
        for (int nf = 0; nf < 2; ++nf)
          acc[mf][nf] = mfma_bf16(a[mf], b[nf], acc[mf][nf]);
    }
    __syncthreads();
  }

  const float* bias = (p == 0 ? bq : (p == 1 ? bk : bv)) + h * 64;
  // q pre-scaled by (1/sqrt(DH)) * LOG2E so attention softmax is exp2-direct
  const float scale = (p == 0) ? 0.125f * LOG2E : 1.0f;
  float bvv[2];
#pragma unroll
  for (int nf = 0; nf < 2; ++nf) bvv[nf] = bias[wn * 32 + nf * 16 + li];
#pragma unroll
  for (int mf = 0; mf < 4; ++mf)
#pragma unroll
    for (int nf = 0; nf < 2; ++nf) {
      int e = wn * 32 + nf * 16 + li;
#pragma unroll
      for (int j = 0; j < 4; ++j) {
        int s = s0 + wm * 64 + mf * 16 + lg * 4 + j;
        unsigned short bf = f2bf((acc[mf][nf][j] + bvv[nf]) * scale);
        if (p == 0)      qo[((size_t)h * 4096 + s) * 64 + e] = bf;
        else if (p == 1) ko[((size_t)h * 4096 + s) * 64 + e] = bf;
        else             vTo[((size_t)h * 64 + e) * 4096 + s] = bf;
      }
    }
}

// ---------------------------------------------------------------------------
// Flash attention v4: split-K x2, LDS-staged K/V, swapped QK^T, in-register
// softmax + P (no P-LDS). grid (768, 2); 4 waves x 16 q-rows; 64-key tiles.
// LDS: K 2x8KB + V 2x8KB = 32KB -> 5 blocks/CU.
__global__ __launch_bounds__(256) void k_attn(
    const unsigned short* __restrict__ q, const unsigned short* __restrict__ k,
    const unsigned short* __restrict__ vT,
    unsigned short* __restrict__ oP, float* __restrict__ mlP) {
  __shared__ __align__(16) char Kb[2][8192];   // [key r][128B dh], swizzled
  __shared__ __align__(16) char Vb[2][8192];   // [dh r][128B keys], swizzled
  const int bid = blockIdx.x;
  const int part = blockIdx.y;
  const int h = bid >> 6, qb = bid & 63;
  const int s0 = qb * 64;
  const int tid = threadIdx.x;
  const int w = tid >> 6, l = tid & 63;
  const int lg = l >> 4, li = l & 15;
  const unsigned short* Kh = k + (size_t)h * 4096 * 64;
  const unsigned short* Vh = vT + (size_t)h * 64 * 4096;

  const int rS = tid >> 3;
  const int bS = (tid & 7) * 16;

  const unsigned short* qrow = q + ((size_t)h * 4096 + s0 + w * 16 + li) * 64;
  frag8 qf0 = *(const frag8*)(qrow + lg * 8);
  frag8 qf1 = *(const frag8*)(qrow + 32 + lg * 8);

  // K fragment row permutation: fragment cn loads LDS key-row
  // kappa = base[cn] + 8*(li>>2) + (li&3), bases {0,4,32,36}. This relabels
  // keys so each lane's 16 P-values are exactly its PV A-frag keys
  // {8lg..8lg+7} u {32+8lg..32+8lg+7} (V unaffected: relabel = permutation).
  const int kRow = 8 * (li >> 2) + (li & 3);

  float m = -1e30f, lsum = 0.f;    // per-lane: own q-row (q = li)
  facc4 acc[4];
#pragma unroll
  for (int nf = 0; nf < 4; ++nf) acc[nf] = (facc4){0.f, 0.f, 0.f, 0.f};

  const int kb0 = part * 2048;

  // prologue: stage tile 0 into buf 0
#pragma unroll
  for (int i = 0; i < 2; ++i) {
    int r = i * 32 + rS;
    int sb = SWZ16(r, bS);
    gld_lds16((const char*)(Kh + (size_t)(kb0 + r) * 64) + sb,
              Kb[0] + i * 4096 + w * 1024);
    gld_lds16((const char*)(Vh + (size_t)r * 4096 + kb0) + sb,
              Vb[0] + i * 4096 + w * 1024);
  }
  __syncthreads();

  int cur = 0;
  for (int kt = 0; kt < 32; ++kt) {
    if (kt < 31) {
      const int kbn = kb0 + (kt + 1) * 64;
#pragma unroll
      for (int i = 0; i < 2; ++i) {
        int r = i * 32 + rS;
        int sb = SWZ16(r, bS);
        gld_lds16((const char*)(Kh + (size_t)(kbn + r) * 64) + sb,
                  Kb[cur ^ 1] + i * 4096 + w * 1024);
        gld_lds16((const char*)(Vh + (size_t)r * 4096 + kbn) + sb,
                  Vb[cur ^ 1] + i * 4096 + w * 1024);
      }
    }
    const char* Kc = Kb[cur];
    const char* Vc = Vb[cur];

    // S^T = K Q^T: sf[cn][j] = score[key=lambda(cn,lg,j)][q=li]
    facc4 sf[4];
#pragma unroll
    for (int cn = 0; cn < 4; ++cn) sf[cn] = (facc4){0.f, 0.f, 0.f, 0.f};
    const int kbase4[4] = {0, 4, 32, 36};
#pragma unroll
    for (int cn = 0; cn < 4; ++cn) {
      int r = kbase4[cn] + kRow;
      frag8 a0 = *(const frag8*)(Kc + r * 128 + SWZ16(r, lg * 16));
      frag8 a1 = *(const frag8*)(Kc + r * 128 + SWZ16(r, 64 + lg * 16));
      sf[cn] = mfma_bf16(a0, qf0, sf[cn]);
      sf[cn] = mfma_bf16(a1, qf1, sf[cn]);
    }
    // in-lane row max (16 values, own q-row) + 2-lane-hop reduce
    float t0 = fmaxf(fmaxf(fmaxf(sf[0][0], sf[0][1]), fmaxf(sf[0][2], sf[0][3])),
                     fmaxf(fmaxf(sf[1][0], sf[1][1]), fmaxf(sf[1][2], sf[1][3])));
    float t1 = fmaxf(fmaxf(fmaxf(sf[2][0], sf[2][1]), fmaxf(sf[2][2], sf[2][3])),
                     fmaxf(fmaxf(sf[3][0], sf[3][1]), fmaxf(sf[3][2], sf[3][3])));
    float tmax = fmaxf(t0, t1);
    tmax = fmaxf(tmax, __shfl_xor(tmax, 16));
    tmax = fmaxf(tmax, __shfl_xor(tmax, 32));
    // defer-max rescale (log2 units)
    if (__any(tmax > m + THR_LOG2)) {
      float mn = fmaxf(m, tmax);
      float corr = EXP2(m - mn);
      m = mn;
      lsum *= corr;
#pragma unroll
      for (int j = 0; j < 4; ++j) {
        float cj = __shfl(corr, (l & 48) | (4 * lg + j));
#pragma unroll
        for (int nf = 0; nf < 4; ++nf) acc[nf][j] *= cj;
      }
    }
    // P = exp2(S - m), in-register; pack to bf16 PV A-frags (lane-local)
    float pv[4][4];
#pragma unroll
    for (int cn = 0; cn < 4; ++cn)
#pragma unroll
      for (int j = 0; j < 4; ++j) {
        pv[cn][j] = EXP2(sf[cn][j] - m);
        lsum += pv[cn][j];
      }
    uint4v u0, u1;
    u0[0] = cvt_pk_bf16(pv[0][0], pv[0][1]);
    u0[1] = cvt_pk_bf16(pv[0][2], pv[0][3]);
    u0[2] = cvt_pk_bf16(pv[1][0], pv[1][1]);
    u0[3] = cvt_pk_bf16(pv[1][2], pv[1][3]);
    u1[0] = cvt_pk_bf16(pv[2][0], pv[2][1]);
    u1[1] = cvt_pk_bf16(pv[2][2], pv[2][3]);
    u1[2] = cvt_pk_bf16(pv[3][0], pv[3][1]);
    u1[3] = cvt_pk_bf16(pv[3][2], pv[3][3]);
    frag8 pa0 = __builtin_bit_cast(frag8, u0);
    frag8 pa1 = __builtin_bit_cast(frag8, u1);
    // ctx += P * V
#pragma unroll
    for (int nf = 0; nf < 4; ++nf) {
      int rv = nf * 16 + li;
      frag8 vb0 = *(const frag8*)(Vc + rv * 128 + SWZ16(rv, lg * 16));
      frag8 vb1 = *(const frag8*)(Vc + rv * 128 + SWZ16(rv, 64 + lg * 16));
      acc[nf] = mfma_bf16(pa0, vb0, acc[nf]);
      acc[nf] = mfma_bf16(pa1, vb1, acc[nf]);
    }
    __syncthreads();
    cur ^= 1;
  }
  // epilogue: total lsum per q-row (4-lane reduce), emit partials
  lsum += __shfl_xor(lsum, 16);
  lsum += __shfl_xor(lsum, 32);
  const size_t base = ((size_t)(part * 12 + h) * 4096 + s0 + w * 16);
  float Lj[4];
#pragma unroll
  for (int j = 0; j < 4; ++j)
    Lj[j] = __shfl(lsum, (l & 48) | (4 * lg + j));
#pragma unroll
  for (int nf = 0; nf < 4; ++nf)
#pragma unroll
    for (int j = 0; j < 4; ++j)
      oP[(base + lg * 4 + j) * 64 + nf * 16 + li] = f2bf(acc[nf][j] / Lj[j]);
  if (lg == 0) {
    mlP[(base + li) * 2 + 0] = m;      // log2 units
    mlP[(base + li) * 2 + 1] = lsum;
  }
}

// ---------------------------------------------------------------------------
// Combine split-K partials -> ctx bf16. m is in log2 units (exp2 weights).
__global__ __launch_bounds__(256) void k_combine(
    const unsigned short* __restrict__ oP, const float* __restrict__ mlP,
    unsigned short* __restrict__ ctx) {
  const int tid = threadIdx.x;
  const int rg = blockIdx.x * 4 + (tid >> 6);
  const int e = tid & 63;
  const int h = rg >> 12, s = rg & 4095;
  const size_t r0 = (size_t)h * 4096 + s;
  const size_t r1 = (size_t)(12 + h) * 4096 + s;
  float m0 = mlP[r0 * 2], l0 = mlP[r0 * 2 + 1];
  float m1 = mlP[r1 * 2], l1 = mlP[r1 * 2 + 1];
  float M = fmaxf(m0, m1);
  float w0 = l0 * EXP2(m0 - M);
  float w1 = l1 * EXP2(m1 - M);
  float inv = 1.f / (w0 + w1);
  float o = (w0 * bf2f(oP[r0 * 64 + e]) + w1 * bf2f(oP[r1 * 64 + e])) * inv;
  ctx[(size_t)s * 768 + h * 64 + e] = f2bf(o);
}

// ---------------------------------------------------------------------------
__global__ __launch_bounds__(256) void k_proj(
    const unsigned short* __restrict__ ctx, const unsigned short* __restrict__ woT,
    const float* __restrict__ bo, float* __restrict__ out) {
  __shared__ __align__(16) unsigned short As[64 * 72];
  __shared__ __align__(16) unsigned short Bs[64 * 72];
  const int s0 = blockIdx.x * 64, j0 = blockIdx.y * 64;
  const int tid = threadIdx.x;
  const int w = tid >> 6, l = tid & 63;
  const int lg = l >> 4, li = l & 15;
  const int wm = w >> 1, wn = w & 1;
  facc4 acc[2][2];
#pragma unroll
  for (int i = 0; i < 2; ++i)
#pragma unroll
    for (int j = 0; j < 2; ++j) acc[i][j] = (facc4){0.f, 0.f, 0.f, 0.f};

  const int rA = tid >> 3;
  const int c8 = (tid & 7) * 8;

  for (int k0 = 0; k0 < 768; k0 += 64) {
    frag8 av[2], bw[2];
#pragma unroll
    for (int i = 0; i < 2; ++i) {
      av[i] = *(const frag8*)(ctx + (size_t)(s0 + i * 32 + rA) * 768 + k0 + c8);
      bw[i] = *(const frag8*)(woT + (size_t)(j0 + i * 32 + rA) * 768 + k0 + c8);
    }
#pragma unroll
    for (int i = 0; i < 2; ++i) {
      *(frag8*)(&As[(i * 32 + rA) * 72 + c8]) = av[i];
      *(frag8*)(&Bs[(i * 32 + rA) * 72 + c8]) = bw[i];
    }
    __syncthreads();
#pragma unroll
    for (int kk = 0; kk < 2; ++kk) {
      const int ce = kk * 32 + lg * 8;
      frag8 a[2], b[2];
#pragma unroll
      for (int mf = 0; mf < 2; ++mf)
        a[mf] = *(const frag8*)(&As[(wm * 32 + mf * 16 + li) * 72 + ce]);
#pragma unroll
      for (int nf = 0; nf < 2; ++nf)
        b[nf] = *(const frag8*)(&Bs[(wn * 32 + nf * 16 + li) * 72 + ce]);
#pragma unroll
      for (int mf = 0; mf < 2; ++mf)
#pragma unroll
        for (int nf = 0; nf < 2; ++nf)
          acc[mf][nf] = mfma_bf16(a[mf], b[nf], acc[mf][nf]);
    }
    __syncthreads();
  }
#pragma unroll
  for (int nf = 0; nf < 2; ++nf) {
    int jc = j0 + wn * 32 + nf * 16 + li;
    float bb = bo[jc];
#pragma unroll
    for (int mf = 0; mf < 2; ++mf)
#pragma unroll
      for (int j = 0; j < 4; ++j) {
        int s = s0 + wm * 32 + mf * 16 + lg * 4 + j;
        out[(size_t)s * 768 + jc] = acc[mf][nf][j] + bb;   // F32 STORE
      }
  }
}

// ---------------------------------------------------------------------------
extern "C" void kernel_launch(void* const* d_in, const int* in_sizes, int n_in,
                              void* d_out, int out_size, void* d_ws, size_t ws_size,
                              hipStream_t stream) {
  const float* x  = (const float*)d_in[0];
  const float* wq = (const float*)d_in[1];
  const float* bq = (const float*)d_in[2];
  const float* wk = (const float*)d_in[3];
  const float* bk = (const float*)d_in[4];
  const float* wv = (const float*)d_in[5];
  const float* bv = (const float*)d_in[6];
  const float* wo = (const float*)d_in[7];
  const float* bo = (const float*)d_in[8];
  float* out = (float*)d_out;   // F32 output (proven)

  char* ws = (char*)d_ws;
  unsigned short* xb  = (unsigned short*)(ws);
  unsigned short* wT  = (unsigned short*)(ws + 6291456);
  unsigned short* woT = (unsigned short*)(ws + 9830400);
  unsigned short* qd  = (unsigned short*)(ws + 11010048);
  unsigned short* kd  = (unsigned short*)(ws + 17301504);
  unsigned short* vTd = (unsigned short*)(ws + 23592960);
  unsigned short* ctx = (unsigned short*)(ws + 29884416);
  unsigned short* oP  = (unsigned short*)(ws + 36175872);
  float*          mlP = (float*)(ws + 48758784);

  k_cvt_x<<<1536, 256, 0, stream>>>(x, xb);
  k_prep_w<<<576, 256, 0, stream>>>(wq, wk, wv, wo,
                                    wT, wT + 589824, wT + 1179648, woT);
  k_qkv<<<dim3(32, 36), 256, 0, stream>>>(xb, wT, bq, bk, bv, qd, kd, vTd);
  k_attn<<<dim3(768, 2), 256, 0, stream>>>(qd, kd, vTd, oP, mlP);
  k_combine<<<12288, 256, 0, stream>>>(oP, mlP, ctx);
  k_proj<<<dim3(64, 12), 256, 0, stream>>>(ctx, woT, bo, out);
}

// Round 9
// 141.799 us; speedup vs baseline: 2.8504x; 1.1051x over previous
//
#include <hip/hip_runtime.h>

// ---------------------------------------------------------------------------
// MultiHeadedAttention fused pipeline for MI355X (gfx950), bf16 MFMA.
// B=1, S=4096, D=768, H=12, DH=64.
// Round 9: k_attn occupancy + bank-conflict fix:
//   - 8-wave blocks (QBLK=128, 512 thr): grid (384,2)=768 = exactly 3/CU,
//     no scheduling tail; K/V staging amortized over 2x q-rows
//   - parity-balanced kappa: r = 8a+b+4*((cn&1)^(a&1))+32*(cn>>1) spreads
//     LDS granule columns (2-way max = free); induced pack swap for odd lg
//     done via 2 facc4 cndmask swaps pre-exp
// Workspace layout unchanged (49545216 bytes).
// ---------------------------------------------------------------------------

using frag8 = __attribute__((ext_vector_type(8))) short;   // 8 x bf16 (4 VGPRs)
using facc4 = __attribute__((ext_vector_type(4))) float;   // MFMA accumulator
using uint4v = __attribute__((ext_vector_type(4))) unsigned int;

#define LOG2E 1.4426950408889634f
#define THR_LOG2 11.5415603f      // 8 * LOG2E (defer-max threshold, log2 units)
#define SWZ16(r, b) ((b) ^ (((r) & 7) << 4))

#if defined(__has_builtin)
#  if __has_builtin(__builtin_amdgcn_exp2f)
#    define EXP2(x) __builtin_amdgcn_exp2f(x)
#  else
#    define EXP2(x) exp2f(x)
#  endif
#else
#  define EXP2(x) exp2f(x)
#endif

__device__ __forceinline__ unsigned short f2bf(float f) {
  unsigned int u = __builtin_bit_cast(unsigned int, f);
  u = (u + 0x7FFFu + ((u >> 16) & 1u)) >> 16;   // RNE
  return (unsigned short)u;
}
__device__ __forceinline__ float bf2f(unsigned short s) {
  unsigned int u = ((unsigned int)s) << 16;
  return __builtin_bit_cast(float, u);
}
__device__ __forceinline__ unsigned cvt_pk_bf16(float lo, float hi) {
  unsigned r;
  asm("v_cvt_pk_bf16_f32 %0, %1, %2" : "=v"(r) : "v"(lo), "v"(hi));
  return r;
}

__device__ __forceinline__ facc4 mfma_bf16(frag8 a, frag8 b, facc4 c) {
  return __builtin_amdgcn_mfma_f32_16x16x32_bf16(a, b, c, 0, 0, 0);
}

__device__ __forceinline__ void gld_lds16(const void* g, void* l) {
  auto gp = (const __attribute__((address_space(1))) unsigned int*)g;
  auto lp = (__attribute__((address_space(3))) unsigned int*)l;
  __builtin_amdgcn_global_load_lds(gp, lp, 16, 0, 0);
}

// ---------------------------------------------------------------------------
__global__ __launch_bounds__(256) void k_cvt_x(const float* __restrict__ in,
                                               unsigned short* __restrict__ out) {
  int i = (blockIdx.x * 256 + threadIdx.x) * 8;
  float4 a = *(const float4*)(in + i);
  float4 b = *(const float4*)(in + i + 4);
  frag8 r;
  r[0] = (short)f2bf(a.x); r[1] = (short)f2bf(a.y);
  r[2] = (short)f2bf(a.z); r[3] = (short)f2bf(a.w);
  r[4] = (short)f2bf(b.x); r[5] = (short)f2bf(b.y);
  r[6] = (short)f2bf(b.z); r[7] = (short)f2bf(b.w);
  *(frag8*)(out + i) = r;
}

// ---------------------------------------------------------------------------
__global__ __launch_bounds__(256) void k_prep_w(
    const float* __restrict__ wq, const float* __restrict__ wk,
    const float* __restrict__ wv, const float* __restrict__ wo,
    unsigned short* __restrict__ wqT, unsigned short* __restrict__ wkT,
    unsigned short* __restrict__ wvT, unsigned short* __restrict__ woT) {
  __shared__ unsigned short tile[64][65];
  const int bx = blockIdx.x;
  const float* src; unsigned short* dst;
  int ld_src, ld_dst, r0, c0;
  if (bx < 432) {
    int p = bx / 144, rem = bx % 144;
    int h = rem / 12, dt = rem % 12;
    src = (p == 0 ? wq : (p == 1 ? wk : wv)) + (size_t)h * 768 * 64;
    dst = (p == 0 ? wqT : (p == 1 ? wkT : wvT)) + (size_t)h * 64 * 768;
    ld_src = 64; ld_dst = 768; r0 = dt * 64; c0 = 0;
  } else {
    int t = bx - 432;
    src = wo; dst = woT;
    ld_src = 768; ld_dst = 768;
    r0 = (t / 12) * 64; c0 = (t % 12) * 64;
  }
  const int tid = threadIdx.x;
  const int lr = tid >> 2, lc0 = (tid & 3) * 16;
#pragma unroll
  for (int i = 0; i < 16; ++i)
    tile[lr][lc0 + i] = f2bf(src[(size_t)(r0 + lr) * ld_src + c0 + lc0 + i]);
  __syncthreads();
  const int oc = tid >> 2;
#pragma unroll
  for (int i = 0; i < 16; ++i)
    dst[(size_t)(c0 + oc) * ld_dst + r0 + lc0 + i] = tile[lc0 + i][oc];
}

// ---------------------------------------------------------------------------
__global__ __launch_bounds__(256) void k_qkv(
    const unsigned short* __restrict__ xb, const unsigned short* __restrict__ wT,
    const float* __restrict__ bq, const float* __restrict__ bk,
    const float* __restrict__ bv,
    unsigned short* __restrict__ qo, unsigned short* __restrict__ ko,
    unsigned short* __restrict__ vTo) {
  __shared__ __align__(16) unsigned short As[128 * 72];
  __shared__ __align__(16) unsigned short Bs[64 * 72];
  const int sb = blockIdx.x, ph = blockIdx.y;
  const int p = ph / 12, h = ph % 12;
  const int s0 = sb * 128;
  const int tid = threadIdx.x;
  const int w = tid >> 6, l = tid & 63;
  const int lg = l >> 4, li = l & 15;
  const int wm = w >> 1, wn = w & 1;
  const unsigned short* wTb = wT + (size_t)ph * 64 * 768;

  facc4 acc[4][2];
#pragma unroll
  for (int i = 0; i < 4; ++i)
#pragma unroll
    for (int j = 0; j < 2; ++j) acc[i][j] = (facc4){0.f, 0.f, 0.f, 0.f};

  const int rA = tid >> 3;
  const int c8 = (tid & 7) * 8;

  for (int k0 = 0; k0 < 768; k0 += 64) {
    frag8 av[4], bw[2];
#pragma unroll
    for (int i = 0; i < 4; ++i)
      av[i] = *(const frag8*)(xb + (size_t)(s0 + i * 32 + rA) * 768 + k0 + c8);
#pragma unroll
    for (int i = 0; i < 2; ++i)
      bw[i] = *(const frag8*)(wTb + (size_t)(i * 32 + rA) * 768 + k0 + c8);
#pragma unroll
    for (int i = 0; i < 4; ++i)
      *(frag8*)(&As[(i * 32 + rA) * 72 + c8]) = av[i];
#pragma unroll
    for (int i = 0; i < 2; ++i)
      *(frag8*)(&Bs[(i * 32 + rA) * 72 + c8]) = bw[i];
    __syncthreads();
#pragma unroll
    for (int kk = 0; kk < 2; ++kk) {
      const int ce = kk * 32 + lg * 8;
      frag8 a[4], b[2];
#pragma unroll
      for (int mf = 0; mf < 4; ++mf)
        a[mf] = *(const frag8*)(&As[(wm * 64 + mf * 16 + li) * 72 + ce]);
#pragma unroll
      for (int nf = 0; nf < 2; ++nf)
        b[nf] = *(const frag8*)(&Bs[(wn * 32 + nf * 16 + li) * 72 + ce]);
#pragma unroll
      for (int mf = 0; mf < 4; ++mf)
#pragma unroll
        for (int nf = 0; nf < 2; ++nf)
          acc[mf][nf] = mfma_bf16(a[mf], b[nf], acc[mf][nf]);
    }
    __syncthreads();
  }

  const float* bias = (p == 0 ? bq : (p == 1 ? bk : bv)) + h * 64;
  // q pre-scaled by (1/sqrt(DH)) * LOG2E so attention softmax is exp2-direct
  const float scale = (p == 0) ? 0.125f * LOG2E : 1.0f;
  float bvv[2];
#pragma unroll
  for (int nf = 0; nf < 2; ++nf) bvv[nf] = bias[wn * 32 + nf * 16 + li];
#pragma unroll
  for (int mf = 0; mf < 4; ++mf)
#pragma unroll
    for (int nf = 0; nf < 2; ++nf) {
      int e = wn * 32 + nf * 16 + li;
#pragma unroll
      for (int j = 0; j < 4; ++j) {
        int s = s0 + wm * 64 + mf * 16 + lg * 4 + j;
        unsigned short bf = f2bf((acc[mf][nf][j] + bvv[nf]) * scale);
        if (p == 0)      qo[((size_t)h * 4096 + s) * 64 + e] = bf;
        else if (p == 1) ko[((size_t)h * 4096 + s) * 64 + e] = bf;
        else             vTo[((size_t)h * 64 + e) * 4096 + s] = bf;
      }
    }
}

// ---------------------------------------------------------------------------
// Flash attention v5: split-K x2, 8-wave blocks (QBLK=128), LDS-staged K/V,
// swapped QK^T + in-register softmax, parity-balanced key relabeling.
// grid (384, 2) x 512 thr; K-tile 64x64, V^T-tile 64x64; LDS 32KB -> 3/CU.
__global__ __launch_bounds__(512) void k_attn(
    const unsigned short* __restrict__ q, const unsigned short* __restrict__ k,
    const unsigned short* __restrict__ vT,
    unsigned short* __restrict__ oP, float* __restrict__ mlP) {
  __shared__ __align__(16) char Kb[2][8192];   // [key r][128B dh], swizzled
  __shared__ __align__(16) char Vb[2][8192];   // [dh r][128B keys], swizzled
  const int bid = blockIdx.x;                   // 384 = 12 h * 32 qb
  const int part = blockIdx.y;
  const int h = bid >> 5, qb = bid & 31;
  const int s0 = qb * 128;
  const int tid = threadIdx.x;
  const int w = tid >> 6, l = tid & 63;
  const int lg = l >> 4, li = l & 15;
  const unsigned short* Kh = k + (size_t)h * 4096 * 64;
  const unsigned short* Vh = vT + (size_t)h * 64 * 4096;

  // staging: 512 threads cover 64 rows x 8 granules in one shot
  const int rS = tid >> 3;            // 0..63
  const int bS = (tid & 7) * 16;
  const int sbS = SWZ16(rS, bS);

  const unsigned short* qrow = q + ((size_t)h * 4096 + s0 + w * 16 + li) * 64;
  frag8 qf0 = *(const frag8*)(qrow + lg * 8);
  frag8 qf1 = *(const frag8*)(qrow + 32 + lg * 8);

  // K fragment row (parity-balanced kappa): fragment cn, lane li (a=li>>2,
  // b=li&3) loads LDS key-row r = 8a + b + 4*((cn&1)^(a&1)) + 32*(cn>>1).
  // Bijective over 64 keys across cn; per-16-lane-phase r&7 covers all 8
  // granule columns twice -> 2-way LDS access (free). Consequence: for odd
  // lg the score fragments are key-swapped (cn0<->1, cn2<->3) -> cndmask
  // swap before exp.
  const int a_ = li >> 2, b_ = li & 3;
  const int r_base = 8 * a_ + b_;
  const int par4 = (a_ & 1) * 4;      // 4*(a&1)

  float m = -1e30f, lsum = 0.f;       // per-lane: own q-row (q = li)
  facc4 acc[4];
#pragma unroll
  for (int nf = 0; nf < 4; ++nf) acc[nf] = (facc4){0.f, 0.f, 0.f, 0.f};

  const int kb0 = part * 2048;

  // prologue: stage tile 0 into buf 0
  gld_lds16((const char*)(Kh + (size_t)(kb0 + rS) * 64) + sbS, Kb[0] + w * 1024);
  gld_lds16((const char*)(Vh + (size_t)rS * 4096 + kb0) + sbS, Vb[0] + w * 1024);
  __syncthreads();

  int cur = 0;
  for (int kt = 0; kt < 32; ++kt) {
    if (kt < 31) {
      const int kbn = kb0 + (kt + 1) * 64;
      gld_lds16((const char*)(Kh + (size_t)(kbn + rS) * 64) + sbS,
                Kb[cur ^ 1] + w * 1024);
      gld_lds16((const char*)(Vh + (size_t)rS * 4096 + kbn) + sbS,
                Vb[cur ^ 1] + w * 1024);
    }
    const char* Kc = Kb[cur];
    const char* Vc = Vb[cur];

    // S^T = K Q^T with kappa-permuted K rows
    facc4 sf[4];
#pragma unroll
    for (int cn = 0; cn < 4; ++cn) {
      int r = r_base + (((cn & 1) == 0) ? par4 : (4 - par4 > 0 ? 4 - 4 * (a_ & 1) : 0));
      // simplify: 4*((cn&1)^(a&1))
      r = r_base + 4 * ((cn & 1) ^ (a_ & 1)) + 32 * (cn >> 1);
      frag8 a0 = *(const frag8*)(Kc + r * 128 + SWZ16(r, lg * 16));
      frag8 a1 = *(const frag8*)(Kc + r * 128 + SWZ16(r, 64 + lg * 16));
      facc4 s = (facc4){0.f, 0.f, 0.f, 0.f};
      s = mfma_bf16(a0, qf0, s);
      s = mfma_bf16(a1, qf1, s);
      sf[cn] = s;
    }
    // odd-lg fragments are key-swapped: normalize so sf[0]=keys 8lg+0..3 etc.
    if (lg & 1) {
      facc4 t = sf[0]; sf[0] = sf[1]; sf[1] = t;
      t = sf[2]; sf[2] = sf[3]; sf[3] = t;
    }
    // in-lane row max + 2-lane-hop reduce
    float t0 = fmaxf(fmaxf(fmaxf(sf[0][0], sf[0][1]), fmaxf(sf[0][2], sf[0][3])),
                     fmaxf(fmaxf(sf[1][0], sf[1][1]), fmaxf(sf[1][2], sf[1][3])));
    float t1 = fmaxf(fmaxf(fmaxf(sf[2][0], sf[2][1]), fmaxf(sf[2][2], sf[2][3])),
                     fmaxf(fmaxf(sf[3][0], sf[3][1]), fmaxf(sf[3][2], sf[3][3])));
    float tmax = fmaxf(t0, t1);
    tmax = fmaxf(tmax, __shfl_xor(tmax, 16));
    tmax = fmaxf(tmax, __shfl_xor(tmax, 32));
    // defer-max rescale (log2 units)
    if (__any(tmax > m + THR_LOG2)) {
      float mn = fmaxf(m, tmax);
      float corr = EXP2(m - mn);
      m = mn;
      lsum *= corr;
#pragma unroll
      for (int j = 0; j < 4; ++j) {
        float cj = __shfl(corr, (l & 48) | (4 * lg + j));
#pragma unroll
        for (int nf = 0; nf < 4; ++nf) acc[nf][j] *= cj;
      }
    }
    // P = exp2(S - m); pack to PV A-frags (lane-local)
    float pv[4][4];
#pragma unroll
    for (int cn = 0; cn < 4; ++cn)
#pragma unroll
      for (int j = 0; j < 4; ++j) {
        pv[cn][j] = EXP2(sf[cn][j] - m);
        lsum += pv[cn][j];
      }
    uint4v u0, u1;
    u0[0] = cvt_pk_bf16(pv[0][0], pv[0][1]);
    u0[1] = cvt_pk_bf16(pv[0][2], pv[0][3]);
    u0[2] = cvt_pk_bf16(pv[1][0], pv[1][1]);
    u0[3] = cvt_pk_bf16(pv[1][2], pv[1][3]);
    u1[0] = cvt_pk_bf16(pv[2][0], pv[2][1]);
    u1[1] = cvt_pk_bf16(pv[2][2], pv[2][3]);
    u1[2] = cvt_pk_bf16(pv[3][0], pv[3][1]);
    u1[3] = cvt_pk_bf16(pv[3][2], pv[3][3]);
    frag8 pa0 = __builtin_bit_cast(frag8, u0);
    frag8 pa1 = __builtin_bit_cast(frag8, u1);
    // ctx += P * V
#pragma unroll
    for (int nf = 0; nf < 4; ++nf) {
      int rv = nf * 16 + li;
      frag8 vb0 = *(const frag8*)(Vc + rv * 128 + SWZ16(rv, lg * 16));
      frag8 vb1 = *(const frag8*)(Vc + rv * 128 + SWZ16(rv, 64 + lg * 16));
      acc[nf] = mfma_bf16(pa0, vb0, acc[nf]);
      acc[nf] = mfma_bf16(pa1, vb1, acc[nf]);
    }
    __syncthreads();
    cur ^= 1;
  }
  // epilogue: total lsum per q-row, emit partials
  lsum += __shfl_xor(lsum, 16);
  lsum += __shfl_xor(lsum, 32);
  const size_t base = ((size_t)(part * 12 + h) * 4096 + s0 + w * 16);
  float Lj[4];
#pragma unroll
  for (int j = 0; j < 4; ++j)
    Lj[j] = __shfl(lsum, (l & 48) | (4 * lg + j));
#pragma unroll
  for (int nf = 0; nf < 4; ++nf)
#pragma unroll
    for (int j = 0; j < 4; ++j)
      oP[(base + lg * 4 + j) * 64 + nf * 16 + li] = f2bf(acc[nf][j] / Lj[j]);
  if (lg == 0) {
    mlP[(base + li) * 2 + 0] = m;      // log2 units
    mlP[(base + li) * 2 + 1] = lsum;
  }
}

// ---------------------------------------------------------------------------
// Combine split-K partials -> ctx bf16. m is in log2 units (exp2 weights).
__global__ __launch_bounds__(256) void k_combine(
    const unsigned short* __restrict__ oP, const float* __restrict__ mlP,
    unsigned short* __restrict__ ctx) {
  const int tid = threadIdx.x;
  const int rg = blockIdx.x * 4 + (tid >> 6);
  const int e = tid & 63;
  const int h = rg >> 12, s = rg & 4095;
  const size_t r0 = (size_t)h * 4096 + s;
  const size_t r1 = (size_t)(12 + h) * 4096 + s;
  float m0 = mlP[r0 * 2], l0 = mlP[r0 * 2 + 1];
  float m1 = mlP[r1 * 2], l1 = mlP[r1 * 2 + 1];
  float M = fmaxf(m0, m1);
  float w0 = l0 * EXP2(m0 - M);
  float w1 = l1 * EXP2(m1 - M);
  float inv = 1.f / (w0 + w1);
  float o = (w0 * bf2f(oP[r0 * 64 + e]) + w1 * bf2f(oP[r1 * 64 + e])) * inv;
  ctx[(size_t)s * 768 + h * 64 + e] = f2bf(o);
}

// ---------------------------------------------------------------------------
__global__ __launch_bounds__(256) void k_proj(
    const unsigned short* __restrict__ ctx, const unsigned short* __restrict__ woT,
    const float* __restrict__ bo, float* __restrict__ out) {
  __shared__ __align__(16) unsigned short As[64 * 72];
  __shared__ __align__(16) unsigned short Bs[64 * 72];
  const int s0 = blockIdx.x * 64, j0 = blockIdx.y * 64;
  const int tid = threadIdx.x;
  const int w = tid >> 6, l = tid & 63;
  const int lg = l >> 4, li = l & 15;
  const int wm = w >> 1, wn = w & 1;
  facc4 acc[2][2];
#pragma unroll
  for (int i = 0; i < 2; ++i)
#pragma unroll
    for (int j = 0; j < 2; ++j) acc[i][j] = (facc4){0.f, 0.f, 0.f, 0.f};

  const int rA = tid >> 3;
  const int c8 = (tid & 7) * 8;

  for (int k0 = 0; k0 < 768; k0 += 64) {
    frag8 av[2], bw[2];
#pragma unroll
    for (int i = 0; i < 2; ++i) {
      av[i] = *(const frag8*)(ctx + (size_t)(s0 + i * 32 + rA) * 768 + k0 + c8);
      bw[i] = *(const frag8*)(woT + (size_t)(j0 + i * 32 + rA) * 768 + k0 + c8);
    }
#pragma unroll
    for (int i = 0; i < 2; ++i) {
      *(frag8*)(&As[(i * 32 + rA) * 72 + c8]) = av[i];
      *(frag8*)(&Bs[(i * 32 + rA) * 72 + c8]) = bw[i];
    }
    __syncthreads();
#pragma unroll
    for (int kk = 0; kk < 2; ++kk) {
      const int ce = kk * 32 + lg * 8;
      frag8 a[2], b[2];
#pragma unroll
      for (int mf = 0; mf < 2; ++mf)
        a[mf] = *(const frag8*)(&As[(wm * 32 + mf * 16 + li) * 72 + ce]);
#pragma unroll
      for (int nf = 0; nf < 2; ++nf)
        b[nf] = *(const frag8*)(&Bs[(wn * 32 + nf * 16 + li) * 72 + ce]);
#pragma unroll
      for (int mf = 0; mf < 2; ++mf)
#pragma unroll
        for (int nf = 0; nf < 2; ++nf)
          acc[mf][nf] = mfma_bf16(a[mf], b[nf], acc[mf][nf]);
    }
    __syncthreads();
  }
#pragma unroll
  for (int nf = 0; nf < 2; ++nf) {
    int jc = j0 + wn * 32 + nf * 16 + li;
    float bb = bo[jc];
#pragma unroll
    for (int mf = 0; mf < 2; ++mf)
#pragma unroll
      for (int j = 0; j < 4; ++j) {
        int s = s0 + wm * 32 + mf * 16 + lg * 4 + j;
        out[(size_t)s * 768 + jc] = acc[mf][nf][j] + bb;   // F32 STORE
      }
  }
}

// ---------------------------------------------------------------------------
extern "C" void kernel_launch(void* const* d_in, const int* in_sizes, int n_in,
                              void* d_out, int out_size, void* d_ws, size_t ws_size,
                              hipStream_t stream) {
  const float* x  = (const float*)d_in[0];
  const float* wq = (const float*)d_in[1];
  const float* bq = (const float*)d_in[2];
  const float* wk = (const float*)d_in[3];
  const float* bk = (const float*)d_in[4];
  const float* wv = (const float*)d_in[5];
  const float* bv = (const float*)d_in[6];
  const float* wo = (const float*)d_in[7];
  const float* bo = (const float*)d_in[8];
  float* out = (float*)d_out;   // F32 output (proven)

  char* ws = (char*)d_ws;
  unsigned short* xb  = (unsigned short*)(ws);
  unsigned short* wT  = (unsigned short*)(ws + 6291456);
  unsigned short* woT = (unsigned short*)(ws + 9830400);
  unsigned short* qd  = (unsigned short*)(ws + 11010048);
  unsigned short* kd  = (unsigned short*)(ws + 17301504);
  unsigned short* vTd = (unsigned short*)(ws + 23592960);
  unsigned short* ctx = (unsigned short*)(ws + 29884416);
  unsigned short* oP  = (unsigned short*)(ws + 36175872);
  float*          mlP = (float*)(ws + 48758784);

  k_cvt_x<<<1536, 256, 0, stream>>>(x, xb);
  k_prep_w<<<576, 256, 0, stream>>>(wq, wk, wv, wo,
                                    wT, wT + 589824, wT + 1179648, woT);
  k_qkv<<<dim3(32, 36), 256, 0, stream>>>(xb, wT, bq, bk, bv, qd, kd, vTd);
  k_attn<<<dim3(384, 2), 512, 0, stream>>>(qd, kd, vTd, oP, mlP);
  k_combine<<<12288, 256, 0, stream>>>(oP, mlP, ctx);
  k_proj<<<dim3(64, 12), 256, 0, stream>>>(ctx, woT, bo, out);
}

// Round 10
// 140.405 us; speedup vs baseline: 2.8787x; 1.0099x over previous
//
#include <hip/hip_runtime.h>

// ---------------------------------------------------------------------------
// MultiHeadedAttention fused pipeline for MI355X (gfx950), bf16 MFMA.
// B=1, S=4096, D=768, H=12, DH=64.
// Round 10:
//   - k_attn: lsum via ones-MFMA (row-sum as matmul; -16 VALU/iter, no
//     epilogue shuffles), max3-friendly max tree
//   - k_qkv/k_proj: gld_lds16 + XOR-swizzle staging restored (round-1 code,
//     proven correct by rounds 1/2 absmax equivalence + round-4 oracle)
// Workspace layout unchanged (49545216 bytes).
// ---------------------------------------------------------------------------

using frag8 = __attribute__((ext_vector_type(8))) short;   // 8 x bf16 (4 VGPRs)
using facc4 = __attribute__((ext_vector_type(4))) float;   // MFMA accumulator
using uint4v = __attribute__((ext_vector_type(4))) unsigned int;

#define LOG2E 1.4426950408889634f
#define THR_LOG2 11.5415603f      // 8 * LOG2E (defer-max threshold, log2 units)
#define SWZ16(r, b) ((b) ^ (((r) & 7) << 4))

#if defined(__has_builtin)
#  if __has_builtin(__builtin_amdgcn_exp2f)
#    define EXP2(x) __builtin_amdgcn_exp2f(x)
#  else
#    define EXP2(x) exp2f(x)
#  endif
#else
#  define EXP2(x) exp2f(x)
#endif

__device__ __forceinline__ unsigned short f2bf(float f) {
  unsigned int u = __builtin_bit_cast(unsigned int, f);
  u = (u + 0x7FFFu + ((u >> 16) & 1u)) >> 16;   // RNE
  return (unsigned short)u;
}
__device__ __forceinline__ float bf2f(unsigned short s) {
  unsigned int u = ((unsigned int)s) << 16;
  return __builtin_bit_cast(float, u);
}
__device__ __forceinline__ unsigned cvt_pk_bf16(float lo, float hi) {
  unsigned r;
  asm("v_cvt_pk_bf16_f32 %0, %1, %2" : "=v"(r) : "v"(lo), "v"(hi));
  return r;
}

__device__ __forceinline__ facc4 mfma_bf16(frag8 a, frag8 b, facc4 c) {
  return __builtin_amdgcn_mfma_f32_16x16x32_bf16(a, b, c, 0, 0, 0);
}

__device__ __forceinline__ void gld_lds16(const void* g, void* l) {
  auto gp = (const __attribute__((address_space(1))) unsigned int*)g;
  auto lp = (__attribute__((address_space(3))) unsigned int*)l;
  __builtin_amdgcn_global_load_lds(gp, lp, 16, 0, 0);
}

// ---------------------------------------------------------------------------
__global__ __launch_bounds__(256) void k_cvt_x(const float* __restrict__ in,
                                               unsigned short* __restrict__ out) {
  int i = (blockIdx.x * 256 + threadIdx.x) * 8;
  float4 a = *(const float4*)(in + i);
  float4 b = *(const float4*)(in + i + 4);
  frag8 r;
  r[0] = (short)f2bf(a.x); r[1] = (short)f2bf(a.y);
  r[2] = (short)f2bf(a.z); r[3] = (short)f2bf(a.w);
  r[4] = (short)f2bf(b.x); r[5] = (short)f2bf(b.y);
  r[6] = (short)f2bf(b.z); r[7] = (short)f2bf(b.w);
  *(frag8*)(out + i) = r;
}

// ---------------------------------------------------------------------------
__global__ __launch_bounds__(256) void k_prep_w(
    const float* __restrict__ wq, const float* __restrict__ wk,
    const float* __restrict__ wv, const float* __restrict__ wo,
    unsigned short* __restrict__ wqT, unsigned short* __restrict__ wkT,
    unsigned short* __restrict__ wvT, unsigned short* __restrict__ woT) {
  __shared__ unsigned short tile[64][65];
  const int bx = blockIdx.x;
  const float* src; unsigned short* dst;
  int ld_src, ld_dst, r0, c0;
  if (bx < 432) {
    int p = bx / 144, rem = bx % 144;
    int h = rem / 12, dt = rem % 12;
    src = (p == 0 ? wq : (p == 1 ? wk : wv)) + (size_t)h * 768 * 64;
    dst = (p == 0 ? wqT : (p == 1 ? wkT : wvT)) + (size_t)h * 64 * 768;
    ld_src = 64; ld_dst = 768; r0 = dt * 64; c0 = 0;
  } else {
    int t = bx - 432;
    src = wo; dst = woT;
    ld_src = 768; ld_dst = 768;
    r0 = (t / 12) * 64; c0 = (t % 12) * 64;
  }
  const int tid = threadIdx.x;
  const int lr = tid >> 2, lc0 = (tid & 3) * 16;
#pragma unroll
  for (int i = 0; i < 16; ++i)
    tile[lr][lc0 + i] = f2bf(src[(size_t)(r0 + lr) * ld_src + c0 + lc0 + i]);
  __syncthreads();
  const int oc = tid >> 2;
#pragma unroll
  for (int i = 0; i < 16; ++i)
    dst[(size_t)(c0 + oc) * ld_dst + r0 + lc0 + i] = tile[lc0 + i][oc];
}

// ---------------------------------------------------------------------------
// QKV GEMM, gld_lds16 + swizzle staging (round-1 structure, proven correct).
// grid (32, 36): 128-row s-tile x (proj*12+head). 4 waves as 2x2 -> 64x32.
__global__ __launch_bounds__(256) void k_qkv(
    const unsigned short* __restrict__ xb, const unsigned short* __restrict__ wT,
    const float* __restrict__ bq, const float* __restrict__ bk,
    const float* __restrict__ bv,
    unsigned short* __restrict__ qo, unsigned short* __restrict__ ko,
    unsigned short* __restrict__ vTo) {
  __shared__ __align__(16) unsigned short As[128 * 64];  // 128B rows, swizzled
  __shared__ __align__(16) unsigned short Bs[64 * 64];
  const int sb = blockIdx.x, ph = blockIdx.y;
  const int p = ph / 12, h = ph % 12;
  const int s0 = sb * 128;
  const int tid = threadIdx.x;
  const int w = tid >> 6, l = tid & 63;
  const int lg = l >> 4, li = l & 15;
  const int wm = w >> 1, wn = w & 1;
  const unsigned short* wTb = wT + (size_t)ph * 64 * 768;

  facc4 acc[4][2];
#pragma unroll
  for (int i = 0; i < 4; ++i)
#pragma unroll
    for (int j = 0; j < 2; ++j) acc[i][j] = (facc4){0.f, 0.f, 0.f, 0.f};

  const int rA = tid >> 3;              // staging row within 32-row chunk
  const int cbp = (tid & 7) * 16;       // physical col byte (16B granule)

  for (int k0 = 0; k0 < 768; k0 += 64) {
#pragma unroll
    for (int i = 0; i < 4; ++i) {
      int r = i * 32 + rA;
      gld_lds16((const char*)(xb + (size_t)(s0 + r) * 768 + k0) + SWZ16(r, cbp),
                (char*)As + i * 4096 + w * 1024);
    }
#pragma unroll
    for (int i = 0; i < 2; ++i) {
      int r = i * 32 + rA;
      gld_lds16((const char*)(wTb + (size_t)r * 768 + k0) + SWZ16(r, cbp),
                (char*)Bs + i * 4096 + w * 1024);
    }
    __syncthreads();   // drains vmcnt(0): staging visible
#pragma unroll
    for (int kk = 0; kk < 2; ++kk) {
      const int cbl = kk * 64 + lg * 16;
      frag8 a[4], b[2];
#pragma unroll
      for (int mf = 0; mf < 4; ++mf) {
        int r = wm * 64 + mf * 16 + li;
        a[mf] = *(const frag8*)((const char*)As + r * 128 + SWZ16(r, cbl));
      }
#pragma unroll
      for (int nf = 0; nf < 2; ++nf) {
        int r = wn * 32 + nf * 16 + li;
        b[nf] = *(const frag8*)((const char*)Bs + r * 128 + SWZ16(r, cbl));
      }
#pragma unroll
      for (int mf = 0; mf < 4; ++mf)
#pragma unroll
        for (int nf = 0; nf < 2; ++nf)
          acc[mf][nf] = mfma_bf16(a[mf], b[nf], acc[mf][nf]);
    }
    __syncthreads();
  }

  const float* bias = (p == 0 ? bq : (p == 1 ? bk : bv)) + h * 64;
  // q pre-scaled by (1/sqrt(DH)) * LOG2E so attention softmax is exp2-direct
  const float scale = (p == 0) ? 0.125f * LOG2E : 1.0f;
  float bvv[2];
#pragma unroll
  for (int nf = 0; nf < 2; ++nf) bvv[nf] = bias[wn * 32 + nf * 16 + li];
#pragma unroll
  for (int mf = 0; mf < 4; ++mf)
#pragma unroll
    for (int nf = 0; nf < 2; ++nf) {
      int e = wn * 32 + nf * 16 + li;
#pragma unroll
      for (int j = 0; j < 4; ++j) {
        int s = s0 + wm * 64 + mf * 16 + lg * 4 + j;
        unsigned short bf = f2bf((acc[mf][nf][j] + bvv[nf]) * scale);
        if (p == 0)      qo[((size_t)h * 4096 + s) * 64 + e] = bf;
        else if (p == 1) ko[((size_t)h * 4096 + s) * 64 + e] = bf;
        else             vTo[((size_t)h * 64 + e) * 4096 + s] = bf;
      }
    }
}

// ---------------------------------------------------------------------------
// Flash attention v6: split-K x2, 8-wave blocks (QBLK=128), LDS-staged K/V,
// swapped QK^T, in-register softmax, lsum via ones-MFMA.
// grid (384, 2) x 512 thr; LDS 32KB -> 3/CU exact.
__global__ __launch_bounds__(512) void k_attn(
    const unsigned short* __restrict__ q, const unsigned short* __restrict__ k,
    const unsigned short* __restrict__ vT,
    unsigned short* __restrict__ oP, float* __restrict__ mlP) {
  __shared__ __align__(16) char Kb[2][8192];   // [key r][128B dh], swizzled
  __shared__ __align__(16) char Vb[2][8192];   // [dh r][128B keys], swizzled
  const int bid = blockIdx.x;                   // 384 = 12 h * 32 qb
  const int part = blockIdx.y;
  const int h = bid >> 5, qb = bid & 31;
  const int s0 = qb * 128;
  const int tid = threadIdx.x;
  const int w = tid >> 6, l = tid & 63;
  const int lg = l >> 4, li = l & 15;
  const unsigned short* Kh = k + (size_t)h * 4096 * 64;
  const unsigned short* Vh = vT + (size_t)h * 64 * 4096;

  // staging: 512 threads cover 64 rows x 8 granules in one shot
  const int rS = tid >> 3;            // 0..63
  const int bS = (tid & 7) * 16;
  const int sbS = SWZ16(rS, bS);

  const unsigned short* qrow = q + ((size_t)h * 4096 + s0 + w * 16 + li) * 64;
  frag8 qf0 = *(const frag8*)(qrow + lg * 8);
  frag8 qf1 = *(const frag8*)(qrow + 32 + lg * 8);

  // ones B-fragment for lsum row-sum MFMA
  frag8 onesf;
#pragma unroll
  for (int i = 0; i < 8; ++i) onesf[i] = (short)0x3F80;

  // parity-balanced kappa: fragment cn, lane li (a=li>>2, b=li&3) loads LDS
  // key-row r = 8a + b + 4*((cn&1)^(a&1)) + 32*(cn>>1). Bijective; 2-way LDS.
  // Odd-lg fragments are key-swapped -> normalize with 2 facc4 swaps pre-exp.
  const int a_ = li >> 2, b_ = li & 3;
  const int r_base = 8 * a_ + b_;

  float m = -1e30f;                   // per-lane: own q-row (q = li), log2 units
  facc4 acc[4];
  facc4 accl = (facc4){0.f, 0.f, 0.f, 0.f};   // accl[j] = lsum for q-row lg*4+j
#pragma unroll
  for (int nf = 0; nf < 4; ++nf) acc[nf] = (facc4){0.f, 0.f, 0.f, 0.f};

  const int kb0 = part * 2048;

  // prologue: stage tile 0 into buf 0
  gld_lds16((const char*)(Kh + (size_t)(kb0 + rS) * 64) + sbS, Kb[0] + w * 1024);
  gld_lds16((const char*)(Vh + (size_t)rS * 4096 + kb0) + sbS, Vb[0] + w * 1024);
  __syncthreads();

  int cur = 0;
  for (int kt = 0; kt < 32; ++kt) {
    if (kt < 31) {
      const int kbn = kb0 + (kt + 1) * 64;
      gld_lds16((const char*)(Kh + (size_t)(kbn + rS) * 64) + sbS,
                Kb[cur ^ 1] + w * 1024);
      gld_lds16((const char*)(Vh + (size_t)rS * 4096 + kbn) + sbS,
                Vb[cur ^ 1] + w * 1024);
    }
    const char* Kc = Kb[cur];
    const char* Vc = Vb[cur];

    // S^T = K Q^T with kappa-permuted K rows
    facc4 sf[4];
#pragma unroll
    for (int cn = 0; cn < 4; ++cn) {
      int r = r_base + 4 * ((cn & 1) ^ (a_ & 1)) + 32 * (cn >> 1);
      frag8 a0 = *(const frag8*)(Kc + r * 128 + SWZ16(r, lg * 16));
      frag8 a1 = *(const frag8*)(Kc + r * 128 + SWZ16(r, 64 + lg * 16));
      facc4 s = (facc4){0.f, 0.f, 0.f, 0.f};
      s = mfma_bf16(a0, qf0, s);
      s = mfma_bf16(a1, qf1, s);
      sf[cn] = s;
    }
    if (lg & 1) {
      facc4 t = sf[0]; sf[0] = sf[1]; sf[1] = t;
      t = sf[2]; sf[2] = sf[3]; sf[3] = t;
    }
    // in-lane row max (max3-chain: 7x v_max3 + 1 max) + 2-lane-hop reduce
    float t = fmaxf(fmaxf(sf[0][0], sf[0][1]), sf[0][2]);
    t = fmaxf(fmaxf(t, sf[0][3]), sf[1][0]);
    t = fmaxf(fmaxf(t, sf[1][1]), sf[1][2]);
    t = fmaxf(fmaxf(t, sf[1][3]), sf[2][0]);
    t = fmaxf(fmaxf(t, sf[2][1]), sf[2][2]);
    t = fmaxf(fmaxf(t, sf[2][3]), sf[3][0]);
    t = fmaxf(fmaxf(t, sf[3][1]), sf[3][2]);
    float tmax = fmaxf(t, sf[3][3]);
    tmax = fmaxf(tmax, __shfl_xor(tmax, 16));
    tmax = fmaxf(tmax, __shfl_xor(tmax, 32));
    // defer-max rescale (log2 units)
    if (__any(tmax > m + THR_LOG2)) {
      float mn = fmaxf(m, tmax);
      float corr = EXP2(m - mn);
      m = mn;
#pragma unroll
      for (int j = 0; j < 4; ++j) {
        float cj = __shfl(corr, (l & 48) | (4 * lg + j));
        accl[j] *= cj;
#pragma unroll
        for (int nf = 0; nf < 4; ++nf) acc[nf][j] *= cj;
      }
    }
    // P = exp2(S - m); pack to PV A-frags (lane-local)
    float pv[4][4];
#pragma unroll
    for (int cn = 0; cn < 4; ++cn)
#pragma unroll
      for (int j = 0; j < 4; ++j)
        pv[cn][j] = EXP2(sf[cn][j] - m);
    uint4v u0, u1;
    u0[0] = cvt_pk_bf16(pv[0][0], pv[0][1]);
    u0[1] = cvt_pk_bf16(pv[0][2], pv[0][3]);
    u0[2] = cvt_pk_bf16(pv[1][0], pv[1][1]);
    u0[3] = cvt_pk_bf16(pv[1][2], pv[1][3]);
    u1[0] = cvt_pk_bf16(pv[2][0], pv[2][1]);
    u1[1] = cvt_pk_bf16(pv[2][2], pv[2][3]);
    u1[2] = cvt_pk_bf16(pv[3][0], pv[3][1]);
    u1[3] = cvt_pk_bf16(pv[3][2], pv[3][3]);
    frag8 pa0 = __builtin_bit_cast(frag8, u0);
    frag8 pa1 = __builtin_bit_cast(frag8, u1);
    // lsum row-sums via ones-MFMA (accl[j] -> q-row lg*4+j, D-layout direct)
    accl = mfma_bf16(pa0, onesf, accl);
    accl = mfma_bf16(pa1, onesf, accl);
    // ctx += P * V
#pragma unroll
    for (int nf = 0; nf < 4; ++nf) {
      int rv = nf * 16 + li;
      frag8 vb0 = *(const frag8*)(Vc + rv * 128 + SWZ16(rv, lg * 16));
      frag8 vb1 = *(const frag8*)(Vc + rv * 128 + SWZ16(rv, 64 + lg * 16));
      acc[nf] = mfma_bf16(pa0, vb0, acc[nf]);
      acc[nf] = mfma_bf16(pa1, vb1, acc[nf]);
    }
    __syncthreads();
    cur ^= 1;
  }
  // epilogue: accl[j] already holds per-row lsum in D-layout
  const size_t base = ((size_t)(part * 12 + h) * 4096 + s0 + w * 16);
#pragma unroll
  for (int nf = 0; nf < 4; ++nf)
#pragma unroll
    for (int j = 0; j < 4; ++j)
      oP[(base + lg * 4 + j) * 64 + nf * 16 + li] = f2bf(acc[nf][j] / accl[j]);
  if (lg == 0)
    mlP[(base + li) * 2 + 0] = m;          // m for q-row li (log2 units)
  if (li == 0) {
#pragma unroll
    for (int j = 0; j < 4; ++j)
      mlP[(base + lg * 4 + j) * 2 + 1] = accl[j];
  }
}

// ---------------------------------------------------------------------------
// Combine split-K partials -> ctx bf16. m is in log2 units (exp2 weights).
__global__ __launch_bounds__(256) void k_combine(
    const unsigned short* __restrict__ oP, const float* __restrict__ mlP,
    unsigned short* __restrict__ ctx) {
  const int tid = threadIdx.x;
  const int rg = blockIdx.x * 4 + (tid >> 6);
  const int e = tid & 63;
  const int h = rg >> 12, s = rg & 4095;
  const size_t r0 = (size_t)h * 4096 + s;
  const size_t r1 = (size_t)(12 + h) * 4096 + s;
  float m0 = mlP[r0 * 2], l0 = mlP[r0 * 2 + 1];
  float m1 = mlP[r1 * 2], l1 = mlP[r1 * 2 + 1];
  float M = fmaxf(m0, m1);
  float w0 = l0 * EXP2(m0 - M);
  float w1 = l1 * EXP2(m1 - M);
  float inv = 1.f / (w0 + w1);
  float o = (w0 * bf2f(oP[r0 * 64 + e]) + w1 * bf2f(oP[r1 * 64 + e])) * inv;
  ctx[(size_t)s * 768 + h * 64 + e] = f2bf(o);
}

// ---------------------------------------------------------------------------
// Output projection, gld_lds16 + swizzle staging (round-1 structure + f32 out).
__global__ __launch_bounds__(256) void k_proj(
    const unsigned short* __restrict__ ctx, const unsigned short* __restrict__ woT,
    const float* __restrict__ bo, float* __restrict__ out) {
  __shared__ __align__(16) unsigned short As[64 * 64];
  __shared__ __align__(16) unsigned short Bs[64 * 64];
  const int s0 = blockIdx.x * 64, j0 = blockIdx.y * 64;
  const int tid = threadIdx.x;
  const int w = tid >> 6, l = tid & 63;
  const int lg = l >> 4, li = l & 15;
  const int wm = w >> 1, wn = w & 1;
  facc4 acc[2][2];
#pragma unroll
  for (int i = 0; i < 2; ++i)
#pragma unroll
    for (int j = 0; j < 2; ++j) acc[i][j] = (facc4){0.f, 0.f, 0.f, 0.f};

  const int rA = tid >> 3;
  const int cbp = (tid & 7) * 16;

  for (int k0 = 0; k0 < 768; k0 += 64) {
#pragma unroll
    for (int i = 0; i < 2; ++i) {
      int r = i * 32 + rA;
      gld_lds16((const char*)(ctx + (size_t)(s0 + r) * 768 + k0) + SWZ16(r, cbp),
                (char*)As + i * 4096 + w * 1024);
      gld_lds16((const char*)(woT + (size_t)(j0 + r) * 768 + k0) + SWZ16(r, cbp),
                (char*)Bs + i * 4096 + w * 1024);
    }
    __syncthreads();
#pragma unroll
    for (int kk = 0; kk < 2; ++kk) {
      const int cbl = kk * 64 + lg * 16;
      frag8 a[2], b[2];
#pragma unroll
      for (int mf = 0; mf < 2; ++mf) {
        int r = wm * 32 + mf * 16 + li;
        a[mf] = *(const frag8*)((const char*)As + r * 128 + SWZ16(r, cbl));
      }
#pragma unroll
      for (int nf = 0; nf < 2; ++nf) {
        int r = wn * 32 + nf * 16 + li;
        b[nf] = *(const frag8*)((const char*)Bs + r * 128 + SWZ16(r, cbl));
      }
#pragma unroll
      for (int mf = 0; mf < 2; ++mf)
#pragma unroll
        for (int nf = 0; nf < 2; ++nf)
          acc[mf][nf] = mfma_bf16(a[mf], b[nf], acc[mf][nf]);
    }
    __syncthreads();
  }
#pragma unroll
  for (int nf = 0; nf < 2; ++nf) {
    int jc = j0 + wn * 32 + nf * 16 + li;
    float bb = bo[jc];
#pragma unroll
    for (int mf = 0; mf < 2; ++mf)
#pragma unroll
      for (int j = 0; j < 4; ++j) {
        int s = s0 + wm * 32 + mf * 16 + lg * 4 + j;
        out[(size_t)s * 768 + jc] = acc[mf][nf][j] + bb;   // F32 STORE
      }
  }
}

// ---------------------------------------------------------------------------
extern "C" void kernel_launch(void* const* d_in, const int* in_sizes, int n_in,
                              void* d_out, int out_size, void* d_ws, size_t ws_size,
                              hipStream_t stream) {
  const float* x  = (const float*)d_in[0];
  const float* wq = (const float*)d_in[1];
  const float* bq = (const float*)d_in[2];
  const float* wk = (const float*)d_in[3];
  const float* bk = (const float*)d_in[4];
  const float* wv = (const float*)d_in[5];
  const float* bv = (const float*)d_in[6];
  const float* wo = (const float*)d_in[7];
  const float* bo = (const float*)d_in[8];
  float* out = (float*)d_out;   // F32 output (proven)

  char* ws = (char*)d_ws;
  unsigned short* xb  = (unsigned short*)(ws);
  unsigned short* wT  = (unsigned short*)(ws + 6291456);
  unsigned short* woT = (unsigned short*)(ws + 9830400);
  unsigned short* qd  = (unsigned short*)(ws + 11010048);
  unsigned short* kd  = (unsigned short*)(ws + 17301504);
  unsigned short* vTd = (unsigned short*)(ws + 23592960);
  unsigned short* ctx = (unsigned short*)(ws + 29884416);
  unsigned short* oP  = (unsigned short*)(ws + 36175872);
  float*          mlP = (float*)(ws + 48758784);

  k_cvt_x<<<1536, 256, 0, stream>>>(x, xb);
  k_prep_w<<<576, 256, 0, stream>>>(wq, wk, wv, wo,
                                    wT, wT + 589824, wT + 1179648, woT);
  k_qkv<<<dim3(32, 36), 256, 0, stream>>>(xb, wT, bq, bk, bv, qd, kd, vTd);
  k_attn<<<dim3(384, 2), 512, 0, stream>>>(qd, kd, vTd, oP, mlP);
  k_combine<<<12288, 256, 0, stream>>>(oP, mlP, ctx);
  k_proj<<<dim3(64, 12), 256, 0, stream>>>(ctx, woT, bo, out);
}

// Round 11
// 137.148 us; speedup vs baseline: 2.9471x; 1.0237x over previous
//
#include <hip/hip_runtime.h>

// ---------------------------------------------------------------------------
// MultiHeadedAttention fused pipeline for MI355X (gfx950), bf16 MFMA.
// B=1, S=4096, D=768, H=12, DH=64.
// Round 11: k_attn addressing-VALU elimination:
//   - all 16 LDS read offsets hoisted to registers (loop-invariant)
//   - K-loop hand-unrolled x2; buffer select = compile-time imm offset
//   - staging via 2 incremented global pointers (+8192B K / +128B V per tile)
//   - s_setprio(1) around MFMA clusters (T5)
// Workspace layout unchanged (49545216 bytes).
// ---------------------------------------------------------------------------

using frag8 = __attribute__((ext_vector_type(8))) short;   // 8 x bf16 (4 VGPRs)
using facc4 = __attribute__((ext_vector_type(4))) float;   // MFMA accumulator
using uint4v = __attribute__((ext_vector_type(4))) unsigned int;

#define LOG2E 1.4426950408889634f
#define THR_LOG2 11.5415603f      // 8 * LOG2E (defer-max threshold, log2 units)
#define SWZ16(r, b) ((b) ^ (((r) & 7) << 4))

#if defined(__has_builtin)
#  if __has_builtin(__builtin_amdgcn_exp2f)
#    define EXP2(x) __builtin_amdgcn_exp2f(x)
#  else
#    define EXP2(x) exp2f(x)
#  endif
#else
#  define EXP2(x) exp2f(x)
#endif

__device__ __forceinline__ unsigned short f2bf(float f) {
  unsigned int u = __builtin_bit_cast(unsigned int, f);
  u = (u + 0x7FFFu + ((u >> 16) & 1u)) >> 16;   // RNE
  return (unsigned short)u;
}
__device__ __forceinline__ float bf2f(unsigned short s) {
  unsigned int u = ((unsigned int)s) << 16;
  return __builtin_bit_cast(float, u);
}
__device__ __forceinline__ unsigned cvt_pk_bf16(float lo, float hi) {
  unsigned r;
  asm("v_cvt_pk_bf16_f32 %0, %1, %2" : "=v"(r) : "v"(lo), "v"(hi));
  return r;
}

__device__ __forceinline__ facc4 mfma_bf16(frag8 a, frag8 b, facc4 c) {
  return __builtin_amdgcn_mfma_f32_16x16x32_bf16(a, b, c, 0, 0, 0);
}

__device__ __forceinline__ void gld_lds16(const void* g, void* l) {
  auto gp = (const __attribute__((address_space(1))) unsigned int*)g;
  auto lp = (__attribute__((address_space(3))) unsigned int*)l;
  __builtin_amdgcn_global_load_lds(gp, lp, 16, 0, 0);
}

// ---------------------------------------------------------------------------
__global__ __launch_bounds__(256) void k_cvt_x(const float* __restrict__ in,
                                               unsigned short* __restrict__ out) {
  int i = (blockIdx.x * 256 + threadIdx.x) * 8;
  float4 a = *(const float4*)(in + i);
  float4 b = *(const float4*)(in + i + 4);
  frag8 r;
  r[0] = (short)f2bf(a.x); r[1] = (short)f2bf(a.y);
  r[2] = (short)f2bf(a.z); r[3] = (short)f2bf(a.w);
  r[4] = (short)f2bf(b.x); r[5] = (short)f2bf(b.y);
  r[6] = (short)f2bf(b.z); r[7] = (short)f2bf(b.w);
  *(frag8*)(out + i) = r;
}

// ---------------------------------------------------------------------------
__global__ __launch_bounds__(256) void k_prep_w(
    const float* __restrict__ wq, const float* __restrict__ wk,
    const float* __restrict__ wv, const float* __restrict__ wo,
    unsigned short* __restrict__ wqT, unsigned short* __restrict__ wkT,
    unsigned short* __restrict__ wvT, unsigned short* __restrict__ woT) {
  __shared__ unsigned short tile[64][65];
  const int bx = blockIdx.x;
  const float* src; unsigned short* dst;
  int ld_src, ld_dst, r0, c0;
  if (bx < 432) {
    int p = bx / 144, rem = bx % 144;
    int h = rem / 12, dt = rem % 12;
    src = (p == 0 ? wq : (p == 1 ? wk : wv)) + (size_t)h * 768 * 64;
    dst = (p == 0 ? wqT : (p == 1 ? wkT : wvT)) + (size_t)h * 64 * 768;
    ld_src = 64; ld_dst = 768; r0 = dt * 64; c0 = 0;
  } else {
    int t = bx - 432;
    src = wo; dst = woT;
    ld_src = 768; ld_dst = 768;
    r0 = (t / 12) * 64; c0 = (t % 12) * 64;
  }
  const int tid = threadIdx.x;
  const int lr = tid >> 2, lc0 = (tid & 3) * 16;
#pragma unroll
  for (int i = 0; i < 16; ++i)
    tile[lr][lc0 + i] = f2bf(src[(size_t)(r0 + lr) * ld_src + c0 + lc0 + i]);
  __syncthreads();
  const int oc = tid >> 2;
#pragma unroll
  for (int i = 0; i < 16; ++i)
    dst[(size_t)(c0 + oc) * ld_dst + r0 + lc0 + i] = tile[lc0 + i][oc];
}

// ---------------------------------------------------------------------------
// QKV GEMM, gld_lds16 + swizzle staging. grid (32, 36).
__global__ __launch_bounds__(256) void k_qkv(
    const unsigned short* __restrict__ xb, const unsigned short* __restrict__ wT,
    const float* __restrict__ bq, const float* __restrict__ bk,
    const float* __restrict__ bv,
    unsigned short* __restrict__ qo, unsigned short* __restrict__ ko,
    unsigned short* __restrict__ vTo) {
  __shared__ __align__(16) unsigned short As[128 * 64];  // 128B rows, swizzled
  __shared__ __align__(16) unsigned short Bs[64 * 64];
  const int sb = blockIdx.x, ph = blockIdx.y;
  const int p = ph / 12, h = ph % 12;
  const int s0 = sb * 128;
  const int tid = threadIdx.x;
  const int w = tid >> 6, l = tid & 63;
  const int lg = l >> 4, li = l & 15;
  const int wm = w >> 1, wn = w & 1;
  const unsigned short* wTb = wT + (size_t)ph * 64 * 768;

  facc4 acc[4][2];
#pragma unroll
  for (int i = 0; i < 4; ++i)
#pragma unroll
    for (int j = 0; j < 2; ++j) acc[i][j] = (facc4){0.f, 0.f, 0.f, 0.f};

  const int rA = tid >> 3;              // staging row within 32-row chunk
  const int cbp = (tid & 7) * 16;       // physical col byte (16B granule)

  for (int k0 = 0; k0 < 768; k0 += 64) {
#pragma unroll
    for (int i = 0; i < 4; ++i) {
      int r = i * 32 + rA;
      gld_lds16((const char*)(xb + (size_t)(s0 + r) * 768 + k0) + SWZ16(r, cbp),
                (char*)As + i * 4096 + w * 1024);
    }
#pragma unroll
    for (int i = 0; i < 2; ++i) {
      int r = i * 32 + rA;
      gld_lds16((const char*)(wTb + (size_t)r * 768 + k0) + SWZ16(r, cbp),
                (char*)Bs + i * 4096 + w * 1024);
    }
    __syncthreads();   // drains vmcnt(0): staging visible
#pragma unroll
    for (int kk = 0; kk < 2; ++kk) {
      const int cbl = kk * 64 + lg * 16;
      frag8 a[4], b[2];
#pragma unroll
      for (int mf = 0; mf < 4; ++mf) {
        int r = wm * 64 + mf * 16 + li;
        a[mf] = *(const frag8*)((const char*)As + r * 128 + SWZ16(r, cbl));
      }
#pragma unroll
      for (int nf = 0; nf < 2; ++nf) {
        int r = wn * 32 + nf * 16 + li;
        b[nf] = *(const frag8*)((const char*)Bs + r * 128 + SWZ16(r, cbl));
      }
#pragma unroll
      for (int mf = 0; mf < 4; ++mf)
#pragma unroll
        for (int nf = 0; nf < 2; ++nf)
          acc[mf][nf] = mfma_bf16(a[mf], b[nf], acc[mf][nf]);
    }
    __syncthreads();
  }

  const float* bias = (p == 0 ? bq : (p == 1 ? bk : bv)) + h * 64;
  // q pre-scaled by (1/sqrt(DH)) * LOG2E so attention softmax is exp2-direct
  const float scale = (p == 0) ? 0.125f * LOG2E : 1.0f;
  float bvv[2];
#pragma unroll
  for (int nf = 0; nf < 2; ++nf) bvv[nf] = bias[wn * 32 + nf * 16 + li];
#pragma unroll
  for (int mf = 0; mf < 4; ++mf)
#pragma unroll
    for (int nf = 0; nf < 2; ++nf) {
      int e = wn * 32 + nf * 16 + li;
#pragma unroll
      for (int j = 0; j < 4; ++j) {
        int s = s0 + wm * 64 + mf * 16 + lg * 4 + j;
        unsigned short bf = f2bf((acc[mf][nf][j] + bvv[nf]) * scale);
        if (p == 0)      qo[((size_t)h * 4096 + s) * 64 + e] = bf;
        else if (p == 1) ko[((size_t)h * 4096 + s) * 64 + e] = bf;
        else             vTo[((size_t)h * 64 + e) * 4096 + s] = bf;
      }
    }
}

// ---------------------------------------------------------------------------
// Flash attention v7: split-K x2, 8-wave blocks, LDS-staged K/V, swapped
// QK^T, in-register softmax, lsum via ones-MFMA, HOISTED LDS offsets +
// unroll-x2 compile-time buffer select + setprio around MFMA.
// grid (384, 2) x 512 thr; LDS 32KB -> 3/CU exact.
__global__ __launch_bounds__(512) void k_attn(
    const unsigned short* __restrict__ q, const unsigned short* __restrict__ k,
    const unsigned short* __restrict__ vT,
    unsigned short* __restrict__ oP, float* __restrict__ mlP) {
  __shared__ __align__(16) char Kb[2][8192];   // [key r][128B dh], swizzled
  __shared__ __align__(16) char Vb[2][8192];   // [dh r][128B keys], swizzled
  const int bid = blockIdx.x;                   // 384 = 12 h * 32 qb
  const int part = blockIdx.y;
  const int h = bid >> 5, qb = bid & 31;
  const int s0 = qb * 128;
  const int tid = threadIdx.x;
  const int w = tid >> 6, l = tid & 63;
  const int lg = l >> 4, li = l & 15;
  const unsigned short* Kh = k + (size_t)h * 4096 * 64;
  const unsigned short* Vh = vT + (size_t)h * 64 * 4096;

  // staging: 512 threads cover 64 rows x 8 granules in one shot
  const int rS = tid >> 3;            // 0..63
  const int bS = (tid & 7) * 16;
  const int sbS = SWZ16(rS, bS);

  const unsigned short* qrow = q + ((size_t)h * 4096 + s0 + w * 16 + li) * 64;
  frag8 qf0 = *(const frag8*)(qrow + lg * 8);
  frag8 qf1 = *(const frag8*)(qrow + 32 + lg * 8);

  // ones B-fragment for lsum row-sum MFMA
  frag8 onesf;
#pragma unroll
  for (int i = 0; i < 8; ++i) onesf[i] = (short)0x3F80;

  // parity-balanced kappa (verified rounds 9/10) + HOISTED LDS offsets
  const int a_ = li >> 2, b_ = li & 3;
  const int r_base = 8 * a_ + b_;
  int kOff[4][2], vOff[4][2];
#pragma unroll
  for (int cn = 0; cn < 4; ++cn) {
    int r = r_base + 4 * ((cn & 1) ^ (a_ & 1)) + 32 * (cn >> 1);
    kOff[cn][0] = r * 128 + SWZ16(r, lg * 16);
    kOff[cn][1] = r * 128 + SWZ16(r, 64 + lg * 16);
  }
#pragma unroll
  for (int nf = 0; nf < 4; ++nf) {
    int rv = nf * 16 + li;
    vOff[nf][0] = rv * 128 + SWZ16(rv, lg * 16);
    vOff[nf][1] = rv * 128 + SWZ16(rv, 64 + lg * 16);
  }
  const char* KbC = (const char*)Kb;   // buffer 1 = +8192 imm
  const char* VbC = (const char*)Vb;

  float m = -1e30f;                   // own q-row (q = li), log2 units
  facc4 acc[4];
  facc4 accl = (facc4){0.f, 0.f, 0.f, 0.f};   // accl[j] = lsum, q-row lg*4+j
#pragma unroll
  for (int nf = 0; nf < 4; ++nf) acc[nf] = (facc4){0.f, 0.f, 0.f, 0.f};

  const int kb0 = part * 2048;

  // prologue: stage tile 0 into buf 0; init incremented staging pointers
  gld_lds16((const char*)(Kh + (size_t)(kb0 + rS) * 64) + sbS, (char*)Kb + w * 1024);
  gld_lds16((const char*)(Vh + (size_t)rS * 4096 + kb0) + sbS, (char*)Vb + w * 1024);
  const char* KgN = (const char*)(Kh + (size_t)(kb0 + 64 + rS) * 64) + sbS;
  const char* VgN = (const char*)(Vh + (size_t)rS * 4096 + kb0 + 64) + sbS;
  __syncthreads();

#define ATTN_STEP(BUFB, KT)                                                   \
  {                                                                           \
    if ((KT) < 31) {                                                          \
      gld_lds16(KgN, (char*)Kb + ((BUFB) ^ 8192) + w * 1024);                 \
      gld_lds16(VgN, (char*)Vb + ((BUFB) ^ 8192) + w * 1024);                 \
      KgN += 8192; VgN += 128;                                                \
    }                                                                         \
    facc4 sf[4];                                                              \
    __builtin_amdgcn_s_setprio(1);                                            \
    _Pragma("unroll")                                                         \
    for (int cn = 0; cn < 4; ++cn) {                                          \
      frag8 a0 = *(const frag8*)(KbC + (BUFB) + kOff[cn][0]);                 \
      frag8 a1 = *(const frag8*)(KbC + (BUFB) + kOff[cn][1]);                 \
      facc4 s = (facc4){0.f, 0.f, 0.f, 0.f};                                  \
      s = mfma_bf16(a0, qf0, s);                                              \
      s = mfma_bf16(a1, qf1, s);                                              \
      sf[cn] = s;                                                             \
    }                                                                         \
    __builtin_amdgcn_s_setprio(0);                                            \
    if (lg & 1) {                                                             \
      facc4 t_ = sf[0]; sf[0] = sf[1]; sf[1] = t_;                            \
      t_ = sf[2]; sf[2] = sf[3]; sf[3] = t_;                                  \
    }                                                                         \
    float t = fmaxf(fmaxf(sf[0][0], sf[0][1]), sf[0][2]);                     \
    t = fmaxf(fmaxf(t, sf[0][3]), sf[1][0]);                                  \
    t = fmaxf(fmaxf(t, sf[1][1]), sf[1][2]);                                  \
    t = fmaxf(fmaxf(t, sf[1][3]), sf[2][0]);                                  \
    t = fmaxf(fmaxf(t, sf[2][1]), sf[2][2]);                                  \
    t = fmaxf(fmaxf(t, sf[2][3]), sf[3][0]);                                  \
    t = fmaxf(fmaxf(t, sf[3][1]), sf[3][2]);                                  \
    float tmax = fmaxf(t, sf[3][3]);                                          \
    tmax = fmaxf(tmax, __shfl_xor(tmax, 16));                                 \
    tmax = fmaxf(tmax, __shfl_xor(tmax, 32));                                 \
    if (__any(tmax > m + THR_LOG2)) {                                         \
      float mn = fmaxf(m, tmax);                                              \
      float corr = EXP2(m - mn);                                              \
      m = mn;                                                                 \
      _Pragma("unroll")                                                       \
      for (int j = 0; j < 4; ++j) {                                           \
        float cj = __shfl(corr, (l & 48) | (4 * lg + j));                     \
        accl[j] *= cj;                                                        \
        _Pragma("unroll")                                                     \
        for (int nf = 0; nf < 4; ++nf) acc[nf][j] *= cj;                      \
      }                                                                       \
    }                                                                         \
    float pv[4][4];                                                           \
    _Pragma("unroll")                                                         \
    for (int cn = 0; cn < 4; ++cn)                                            \
      _Pragma("unroll")                                                       \
      for (int j = 0; j < 4; ++j)                                             \
        pv[cn][j] = EXP2(sf[cn][j] - m);                                      \
    uint4v u0, u1;                                                            \
    u0[0] = cvt_pk_bf16(pv[0][0], pv[0][1]);                                  \
    u0[1] = cvt_pk_bf16(pv[0][2], pv[0][3]);                                  \
    u0[2] = cvt_pk_bf16(pv[1][0], pv[1][1]);                                  \
    u0[3] = cvt_pk_bf16(pv[1][2], pv[1][3]);                                  \
    u1[0] = cvt_pk_bf16(pv[2][0], pv[2][1]);                                  \
    u1[1] = cvt_pk_bf16(pv[2][2], pv[2][3]);                                  \
    u1[2] = cvt_pk_bf16(pv[3][0], pv[3][1]);                                  \
    u1[3] = cvt_pk_bf16(pv[3][2], pv[3][3]);                                  \
    frag8 pa0 = __builtin_bit_cast(frag8, u0);                                \
    frag8 pa1 = __builtin_bit_cast(frag8, u1);                                \
    __builtin_amdgcn_s_setprio(1);                                            \
    accl = mfma_bf16(pa0, onesf, accl);                                       \
    accl = mfma_bf16(pa1, onesf, accl);                                       \
    _Pragma("unroll")                                                         \
    for (int nf = 0; nf < 4; ++nf) {                                          \
      frag8 vb0 = *(const frag8*)(VbC + (BUFB) + vOff[nf][0]);                \
      frag8 vb1 = *(const frag8*)(VbC + (BUFB) + vOff[nf][1]);                \
      acc[nf] = mfma_bf16(pa0, vb0, acc[nf]);                                 \
      acc[nf] = mfma_bf16(pa1, vb1, acc[nf]);                                 \
    }                                                                         \
    __builtin_amdgcn_s_setprio(0);                                            \
    __syncthreads();                                                          \
  }

  for (int t2 = 0; t2 < 16; ++t2) {
    ATTN_STEP(0, 2 * t2)
    ATTN_STEP(8192, 2 * t2 + 1)
  }
#undef ATTN_STEP

  // epilogue: accl[j] already holds per-row lsum in D-layout
  const size_t base = ((size_t)(part * 12 + h) * 4096 + s0 + w * 16);
#pragma unroll
  for (int nf = 0; nf < 4; ++nf)
#pragma unroll
    for (int j = 0; j < 4; ++j)
      oP[(base + lg * 4 + j) * 64 + nf * 16 + li] = f2bf(acc[nf][j] / accl[j]);
  if (lg == 0)
    mlP[(base + li) * 2 + 0] = m;          // m for q-row li (log2 units)
  if (li == 0) {
#pragma unroll
    for (int j = 0; j < 4; ++j)
      mlP[(base + lg * 4 + j) * 2 + 1] = accl[j];
  }
}

// ---------------------------------------------------------------------------
// Combine split-K partials -> ctx bf16. m is in log2 units (exp2 weights).
__global__ __launch_bounds__(256) void k_combine(
    const unsigned short* __restrict__ oP, const float* __restrict__ mlP,
    unsigned short* __restrict__ ctx) {
  const int tid = threadIdx.x;
  const int rg = blockIdx.x * 4 + (tid >> 6);
  const int e = tid & 63;
  const int h = rg >> 12, s = rg & 4095;
  const size_t r0 = (size_t)h * 4096 + s;
  const size_t r1 = (size_t)(12 + h) * 4096 + s;
  float m0 = mlP[r0 * 2], l0 = mlP[r0 * 2 + 1];
  float m1 = mlP[r1 * 2], l1 = mlP[r1 * 2 + 1];
  float M = fmaxf(m0, m1);
  float w0 = l0 * EXP2(m0 - M);
  float w1 = l1 * EXP2(m1 - M);
  float inv = 1.f / (w0 + w1);
  float o = (w0 * bf2f(oP[r0 * 64 + e]) + w1 * bf2f(oP[r1 * 64 + e])) * inv;
  ctx[(size_t)s * 768 + h * 64 + e] = f2bf(o);
}

// ---------------------------------------------------------------------------
// Output projection, gld_lds16 + swizzle staging, f32 out.
__global__ __launch_bounds__(256) void k_proj(
    const unsigned short* __restrict__ ctx, const unsigned short* __restrict__ woT,
    const float* __restrict__ bo, float* __restrict__ out) {
  __shared__ __align__(16) unsigned short As[64 * 64];
  __shared__ __align__(16) unsigned short Bs[64 * 64];
  const int s0 = blockIdx.x * 64, j0 = blockIdx.y * 64;
  const int tid = threadIdx.x;
  const int w = tid >> 6, l = tid & 63;
  const int lg = l >> 4, li = l & 15;
  const int wm = w >> 1, wn = w & 1;
  facc4 acc[2][2];
#pragma unroll
  for (int i = 0; i < 2; ++i)
#pragma unroll
    for (int j = 0; j < 2; ++j) acc[i][j] = (facc4){0.f, 0.f, 0.f, 0.f};

  const int rA = tid >> 3;
  const int cbp = (tid & 7) * 16;

  for (int k0 = 0; k0 < 768; k0 += 64) {
#pragma unroll
    for (int i = 0; i < 2; ++i) {
      int r = i * 32 + rA;
      gld_lds16((const char*)(ctx + (size_t)(s0 + r) * 768 + k0) + SWZ16(r, cbp),
                (char*)As + i * 4096 + w * 1024);
      gld_lds16((const char*)(woT + (size_t)(j0 + r) * 768 + k0) + SWZ16(r, cbp),
                (char*)Bs + i * 4096 + w * 1024);
    }
    __syncthreads();
#pragma unroll
    for (int kk = 0; kk < 2; ++kk) {
      const int cbl = kk * 64 + lg * 16;
      frag8 a[2], b[2];
#pragma unroll
      for (int mf = 0; mf < 2; ++mf) {
        int r = wm * 32 + mf * 16 + li;
        a[mf] = *(const frag8*)((const char*)As + r * 128 + SWZ16(r, cbl));
      }
#pragma unroll
      for (int nf = 0; nf < 2; ++nf) {
        int r = wn * 32 + nf * 16 + li;
        b[nf] = *(const frag8*)((const char*)Bs + r * 128 + SWZ16(r, cbl));
      }
#pragma unroll
      for (int mf = 0; mf < 2; ++mf)
#pragma unroll
        for (int nf = 0; nf < 2; ++nf)
          acc[mf][nf] = mfma_bf16(a[mf], b[nf], acc[mf][nf]);
    }
    __syncthreads();
  }
#pragma unroll
  for (int nf = 0; nf < 2; ++nf) {
    int jc = j0 + wn * 32 + nf * 16 + li;
    float bb = bo[jc];
#pragma unroll
    for (int mf = 0; mf < 2; ++mf)
#pragma unroll
      for (int j = 0; j < 4; ++j) {
        int s = s0 + wm * 32 + mf * 16 + lg * 4 + j;
        out[(size_t)s * 768 + jc] = acc[mf][nf][j] + bb;   // F32 STORE
      }
  }
}

// ---------------------------------------------------------------------------
extern "C" void kernel_launch(void* const* d_in, const int* in_sizes, int n_in,
                              void* d_out, int out_size, void* d_ws, size_t ws_size,
                              hipStream_t stream) {
  const float* x  = (const float*)d_in[0];
  const float* wq = (const float*)d_in[1];
  const float* bq = (const float*)d_in[2];
  const float* wk = (const float*)d_in[3];
  const float* bk = (const float*)d_in[4];
  const float* wv = (const float*)d_in[5];
  const float* bv = (const float*)d_in[6];
  const float* wo = (const float*)d_in[7];
  const float* bo = (const float*)d_in[8];
  float* out = (float*)d_out;   // F32 output (proven)

  char* ws = (char*)d_ws;
  unsigned short* xb  = (unsigned short*)(ws);
  unsigned short* wT  = (unsigned short*)(ws + 6291456);
  unsigned short* woT = (unsigned short*)(ws + 9830400);
  unsigned short* qd  = (unsigned short*)(ws + 11010048);
  unsigned short* kd  = (unsigned short*)(ws + 17301504);
  unsigned short* vTd = (unsigned short*)(ws + 23592960);
  unsigned short* ctx = (unsigned short*)(ws + 29884416);
  unsigned short* oP  = (unsigned short*)(ws + 36175872);
  float*          mlP = (float*)(ws + 48758784);

  k_cvt_x<<<1536, 256, 0, stream>>>(x, xb);
  k_prep_w<<<576, 256, 0, stream>>>(wq, wk, wv, wo,
                                    wT, wT + 589824, wT + 1179648, woT);
  k_qkv<<<dim3(32, 36), 256, 0, stream>>>(xb, wT, bq, bk, bv, qd, kd, vTd);
  k_attn<<<dim3(384, 2), 512, 0, stream>>>(qd, kd, vTd, oP, mlP);
  k_combine<<<12288, 256, 0, stream>>>(oP, mlP, ctx);
  k_proj<<<dim3(64, 12), 256, 0, stream>>>(ctx, woT, bo, out);
}